// Round 20
// baseline (121.951 us; speedup 1.0000x reference)
//
#include <hip/hip_runtime.h>
#include <hip/hip_bf16.h>
#include <hip/hip_fp16.h>
#include <stdint.h>

#define EMBED 256
#define HEADS 8
#define LEVELS 4
#define POINTS 4
#define HEAD_DIM 32
#define BS 2
#define LV_TOTAL 13294
#define LQ LV_TOTAL
#define TP 128 /* HEADS*LEVELS*POINTS */
#define M_ROWS (BS * LV_TOTAL) /* 26588 */
#define QPB 32 /* queries per gather block (1 head per block) */

typedef __attribute__((ext_vector_type(8))) short bf16x8;
typedef __attribute__((ext_vector_type(4))) float f32x4;

static __device__ __forceinline__ unsigned short f2bf(float x) {
  __hip_bfloat16 h = __float2bfloat16(x);
  return *reinterpret_cast<unsigned short*>(&h);
}
static __device__ __forceinline__ float bf2f(unsigned short u) {
  return __uint_as_float(((unsigned int)u) << 16);
}
static __device__ __forceinline__ unsigned short f2hbits(float x) {
  __half h = __float2half(x);
  return *reinterpret_cast<unsigned short*>(&h);
}

// v_fma_mix_f32: acc(f32) += f16(sel vs of pk) * f16(low half of w)
#define MIX(acc, pk, w, vs)                                              \
  asm("v_fma_mix_f32 %0, %1, %2, %0 op_sel:[" #vs                        \
      ",0,0] op_sel_hi:[1,1,0]"                                          \
      : "+v"(acc)                                                        \
      : "v"(pk), "v"(w))

// ---------------------------------------------------------------------------
// prep_wt: transpose + convert all weight matrices to bf16 WT[n][k] layout.
// ---------------------------------------------------------------------------
__global__ __launch_bounds__(256) void prep_wt_kernel(
    const float* __restrict__ W_val, const float* __restrict__ W_off,
    const float* __restrict__ W_attn, const float* __restrict__ W_out,
    unsigned short* __restrict__ WT_val, unsigned short* __restrict__ WT_oa,
    unsigned short* __restrict__ WT_out) {
  const int bid = blockIdx.x;
  const int k = threadIdx.x;  // 0..255
  const float* src;
  unsigned short* dst;
  int n, N_src;
  if (bid < 256) {
    src = W_val; dst = WT_val; n = bid; N_src = 256;
  } else if (bid < 512) {
    src = W_off; dst = WT_oa; n = bid - 256; N_src = 256;
  } else if (bid < 640) {
    src = W_attn; dst = WT_oa + 256 * 256; n = bid - 512; N_src = 128;
  } else {
    src = W_out; dst = WT_out; n = bid - 640; N_src = 256;
  }
  dst[n * 256 + k] = f2bf(src[(size_t)k * N_src + n]);
}

// ---------------------------------------------------------------------------
// conv_bf16 (dual): f32 -> bf16 for value (y=0) and query (y=1), 8 elem/thr.
// ---------------------------------------------------------------------------
__global__ __launch_bounds__(256) void conv_bf16_kernel(
    const float* __restrict__ value, const float* __restrict__ query,
    unsigned short* __restrict__ vbf, unsigned short* __restrict__ qbf,
    int n8) {
  int i = blockIdx.x * 256 + threadIdx.x;
  const float* in = blockIdx.y ? query : value;
  unsigned short* out = blockIdx.y ? qbf : vbf;
  if (i < n8) {
    float4 p0 = *(const float4*)(in + (size_t)i * 8);
    float4 p1 = *(const float4*)(in + (size_t)i * 8 + 4);
    uint4 o;
    o.x = (unsigned int)f2bf(p0.x) | ((unsigned int)f2bf(p0.y) << 16);
    o.y = (unsigned int)f2bf(p0.z) | ((unsigned int)f2bf(p0.w) << 16);
    o.z = (unsigned int)f2bf(p1.x) | ((unsigned int)f2bf(p1.y) << 16);
    o.w = (unsigned int)f2bf(p1.z) | ((unsigned int)f2bf(p1.w) << 16);
    *(uint4*)(out + (size_t)i * 8) = o;
  }
}

// ---------------------------------------------------------------------------
// Round-9 GEMM body (PROVEN): one 64-col strip x 128 rows; B panel (32 KB)
// in LDS w/ XOR swizzle; per kk: 2 bf16 A-frags, 4 ds_read_b128, 8 MFMA.
// rowblk passed explicitly (grid transposed: strip = blockIdx.x fastest so
// co-dispatched blocks share the same 128-row A slice -> A L2-resident).
// OUT_MODE: 0=f32, 1=bf16, 2=f16 head-major vh, 3=bf16 head-major oa_h.
// ---------------------------------------------------------------------------
template <int NTOT, int OUT_MODE, bool MASKED, bool SPLIT_BIAS>
static __device__ __forceinline__ void gemm_body(
    unsigned short* bpanel, const unsigned short* __restrict__ Ab,
    const unsigned short* __restrict__ BT, const float* __restrict__ bias0,
    const float* __restrict__ bias1, const uint8_t* __restrict__ mask,
    void* __restrict__ Cv, int M, int strip, int rowblk) {
  const int tid = threadIdx.x;
  const int col0 = strip * 64;

  // ---- stage B panel (64 cols x 256 k, bf16), XOR-swizzled ----
#pragma unroll
  for (int it = 0; it < 8; ++it) {
    int c = it * 256 + tid;  // chunk id 0..2047 (16B chunks)
    int col = c >> 5;        // 0..63
    int kc = c & 31;         // 16B chunk within the col's 512B row
    uint4 vdat = *(const uint4*)(BT + ((size_t)(col0 + col)) * 256 + kc * 8);
    int byteoff = (col << 9) + ((kc << 4) ^ ((col & 7) << 4));
    *(uint4*)((char*)bpanel + byteoff) = vdat;
  }
  __syncthreads();

  const int wave = tid >> 6;
  const int lane = tid & 63;
  const int lr = lane & 15;
  const int kq = lane >> 4;  // 0..3
  const int rowW = rowblk * 128 + wave * 16;
  const int ar0 = min(rowW + lr, M - 1);
  const int ar1 = min(rowW + 64 + lr, M - 1);

  f32x4 acc[2][4];
#pragma unroll
  for (int ri = 0; ri < 2; ++ri)
#pragma unroll
    for (int c = 0; c < 4; ++c) acc[ri][c] = (f32x4){0.f, 0.f, 0.f, 0.f};

#pragma unroll
  for (int kk = 0; kk < 8; ++kk) {
    const int k0 = kk * 32 + kq * 8;
    bf16x8 a0 = *(const bf16x8*)(Ab + (size_t)ar0 * 256 + k0);
    bf16x8 a1 = *(const bf16x8*)(Ab + (size_t)ar1 * 256 + k0);
#pragma unroll
    for (int c = 0; c < 4; ++c) {
      const int col = c * 16 + lr;
      const int byteoff = (col << 9) + (((k0 * 2)) ^ ((col & 7) << 4));
      bf16x8 bfrag = *(const bf16x8*)((const char*)bpanel + byteoff);
      acc[0][c] =
          __builtin_amdgcn_mfma_f32_16x16x32_bf16(a0, bfrag, acc[0][c], 0, 0, 0);
      acc[1][c] =
          __builtin_amdgcn_mfma_f32_16x16x32_bf16(a1, bfrag, acc[1][c], 0, 0, 0);
    }
  }

  // epilogue: D col = lane&15, row = (lane>>4)*4 + i   [m89-verified]
#pragma unroll
  for (int c = 0; c < 4; ++c) {
    const int col = col0 + c * 16 + lr;
    float bv;
    if constexpr (SPLIT_BIAS)
      bv = (col < 256) ? bias0[col] : bias1[col - 256];
    else
      bv = bias0[col];
#pragma unroll
    for (int ri = 0; ri < 2; ++ri) {
#pragma unroll
      for (int i = 0; i < 4; ++i) {
        const int row = rowW + ri * 64 + kq * 4 + i;
        if (row < M) {
          float o = acc[ri][c][i] + bv;
          if constexpr (MASKED) {
            if (mask[row]) o = 0.f;
          }
          if constexpr (OUT_MODE == 0) {
            ((float*)Cv)[(size_t)row * NTOT + col] = o;
          } else if constexpr (OUT_MODE == 1) {
            ((unsigned short*)Cv)[(size_t)row * NTOT + col] = f2bf(o);
          } else if constexpr (OUT_MODE == 2) {
            ((unsigned short*)Cv)[(size_t)(col >> 5) * ((size_t)M * 32) +
                                  (size_t)row * 32 + (col & 31)] = f2hbits(o);
          } else {
            // head-major oa: [h][row][48], off cols 0..31, attn cols 32..47
            int hh, w_;
            if (col < 256) { hh = col >> 5; w_ = col & 31; }
            else { int c2 = col - 256; hh = c2 >> 4; w_ = 32 + (c2 & 15); }
            ((unsigned short*)Cv)[((size_t)hh * M + row) * 48 + w_] = f2bf(o);
          }
        }
      }
    }
  }
}

// fat kernel, grid (10, 208): x = strip (0-3 vproj, 4-9 oa), y = row block.
// Co-dispatched x-neighbors share the same 128-row A slice (L2-resident).
__global__ __launch_bounds__(256) void gemm_fused01_kernel(
    const unsigned short* __restrict__ value_bf,
    const unsigned short* __restrict__ query_bf,
    const unsigned short* __restrict__ wt_val,
    const unsigned short* __restrict__ wt_oa, const float* __restrict__ b_val,
    const float* __restrict__ b_off, const float* __restrict__ b_attn,
    const uint8_t* __restrict__ mask, unsigned short* __restrict__ vh,
    unsigned short* __restrict__ oah, int M) {
  __shared__ uint4 bpanel4[2048];  // 32 KB
  unsigned short* bp = (unsigned short*)bpanel4;
  if (blockIdx.x < 4)
    gemm_body<256, 2, true, false>(bp, value_bf, wt_val, b_val, nullptr, mask,
                                   vh, M, blockIdx.x, blockIdx.y);
  else
    gemm_body<384, 3, false, true>(bp, query_bf, wt_oa, b_off, b_attn,
                                   nullptr, oah, M, blockIdx.x - 4,
                                   blockIdx.y);
}

__global__ __launch_bounds__(256) void gemm_out_kernel(
    const unsigned short* __restrict__ o_in,
    const unsigned short* __restrict__ wt_out, const float* __restrict__ b_out,
    float* __restrict__ out, int M) {
  __shared__ uint4 bpanel4[2048];
  unsigned short* bp = (unsigned short*)bpanel4;
  gemm_body<256, 0, false, false>(bp, o_in, wt_out, b_out, nullptr, nullptr,
                                  out, M, blockIdx.x, blockIdx.y);
}

// ---------------------------------------------------------------------------
// gather_kernel (HEAD-PARTITIONED, round-14 PROVEN): block = 32 queries x
// 1 head x 1 batch, grid (416, 8, 2); vh slice per (head,batch) = 850 KB so
// the instantaneous working set is L2-resident.  oa read from head-major
// oa_h[8][M][48].  Depth-2 ping-pong + sched_barrier(0) inner loop.
// ---------------------------------------------------------------------------
__global__ __launch_bounds__(256) void gather_kernel(
    const float* __restrict__ refpts,
    const __half* __restrict__ vh,           // f16 head-major [8][M][32]
    const unsigned short* __restrict__ oah,  // bf16 head-major [8][M][48]
    unsigned short* __restrict__ o_out) {    // bf16 (BS*LQ, 256)
  __shared__ unsigned short oas[QPB * 48];    // 3 KB raw bf16 [q][48]
  __shared__ float attn_s[QPB][16];           // 2 KB
  __shared__ float ref_s[QPB][LEVELS][2];     // 1 KB
  __shared__ unsigned int meta_idx[QPB][16];  // 2 KB
  __shared__ uint2 meta_w[QPB][16];           // 4 KB

  const int qb = blockIdx.x;  // 0..415
  const int h = blockIdx.y;   // 0..7
  const int b = blockIdx.z;   // 0..1
  const int tid = threadIdx.x;

  // ---- stage oa head-slice: 32 rows x 48 shorts (96 B/row, 6 uint4) ----
  {
    int row = tid >> 3, j = tid & 7;
    if (j < 6) {
      int qg = min(qb * QPB + row, LQ - 1);
      *(uint4*)(oas + row * 48 + j * 8) = *(const uint4*)(
          oah + ((size_t)h * M_ROWS + (size_t)b * LQ + qg) * 48 + j * 8);
    }
  }
  // ---- reference points: 32 q x 8 vals ----
  {
    int q = tid >> 3, rem = tid & 7;
    int qg = min(qb * QPB + q, LQ - 1);
    ref_s[q][rem >> 1][rem & 1] = refpts[((size_t)b * LQ + qg) * 8 + rem];
  }
  __syncthreads();

  // ---- softmax per q over this head's 16 logits (oas cols 32..47) ----
  if (tid < QPB) {
    const unsigned short* arow = oas + tid * 48 + 32;
    float m = bf2f(arow[0]);
#pragma unroll
    for (int i = 1; i < 16; ++i) m = fmaxf(m, bf2f(arow[i]));
    float ssum = 0.f;
#pragma unroll
    for (int i = 0; i < 16; ++i) {
      float e = __expf(bf2f(arow[i]) - m);
      attn_s[tid][i] = e;
      ssum += e;
    }
    float inv = 1.f / ssum;
#pragma unroll
    for (int i = 0; i < 16; ++i) attn_s[tid][i] *= inv;
  }
  __syncthreads();

  // ---- meta precompute: 512 samples (32q x 16), 2 per thread ----
#pragma unroll
  for (int pass = 0; pass < 2; ++pass) {
    const int s = pass * 256 + tid;
    const int q = s >> 4, smp = s & 15;
    const int l = smp >> 2, p = smp & 3;
    const int W = (l == 0) ? 100 : (l == 1) ? 50 : (l == 2) ? 25 : 13;
    const int base = (l == 0) ? 0 : (l == 1) ? 10000 : (l == 2) ? 12500 : 13125;
    const float fW = (float)W;

    float ox = bf2f(oas[q * 48 + l * 8 + p * 2]);
    float oy = bf2f(oas[q * 48 + l * 8 + p * 2 + 1]);
    float rx = ref_s[q][l][0], ry = ref_s[q][l][1];
    float aw = attn_s[q][smp];
    float x = fmaf(rx, fW, ox) - 0.5f;
    float y = fmaf(ry, fW, oy) - 0.5f;  // H == W for all levels
    float x0f = floorf(x), y0f = floorf(y);
    float lw = x - x0f, lh = y - y0f;
    int x0 = (int)x0f, y0 = (int)y0f;
    int x1 = x0 + 1, y1 = y0 + 1;
    int xbase = min(max(x0, 0), W - 2);
    bool x0v = (x0 >= 0) && (x0 < W);
    bool x1v = (x1 >= 0) && (x1 < W);
    float ws0 = ((x0v && x0 == xbase) ? (1.f - lw) : 0.f) +
                ((x1v && x1 == xbase) ? lw : 0.f);
    float ws1 = ((x0v && x0 == xbase + 1) ? (1.f - lw) : 0.f) +
                ((x1v && x1 == xbase + 1) ? lw : 0.f);
    bool y0v = (y0 >= 0) && (y0 < W);
    bool y1v = (y1 >= 0) && (y1 < W);
    int yc0 = min(max(y0, 0), W - 1), yc1 = min(max(y1, 0), W - 1);
    float wy0 = y0v ? (1.f - lh) * aw : 0.f;
    float wy1 = y1v ? lh * aw : 0.f;
    const int posx = smp ^ (q & 7);  // bank swizzle, involution within row
    meta_w[q][posx] = make_uint2(
        (unsigned int)f2hbits(wy0 * ws0) |
            ((unsigned int)f2hbits(wy0 * ws1) << 16),
        (unsigned int)f2hbits(wy1 * ws0) |
            ((unsigned int)f2hbits(wy1 * ws1) << 16));
    meta_idx[q][posx] = (unsigned int)(yc0 * W + xbase + base) |
                        ((unsigned int)(yc1 * W + xbase + base) << 16);
  }
  __syncthreads();

  // ---- gather: lane = ql(8) x tp(8); depth-2 ping-pong, 16 samples ----
  {
    const int lane = tid & 63;
    const int wave = tid >> 6;
    const int ql = lane >> 3;     // query within wave
    const int q = wave * 8 + ql;  // 0..31 block-local query
    const int tp = lane & 7;      // pair-span octet
    const char* vbase = (const char*)vh +
                        ((size_t)h * M_ROWS + (size_t)b * LV_TOTAL) * 64;
    const unsigned int laneoff =
        (unsigned int)(tp >> 2) * 64 + (unsigned int)(tp & 3) * 16;
    const unsigned int sh = (lane & 4) << 2;  // 0 (slot0) or 16 (slot1)

#define PLOAD(C0, C1, IW, WW, smp)                                         \
  {                                                                        \
    const int pos_ = (smp) ^ ql;                                           \
    IW = meta_idx[q][pos_];                                                \
    WW = meta_w[q][pos_];                                                  \
    C0 = *(const uint4*)(vbase + (laneoff + ((IW & 0xffffu) << 6)));       \
    C1 = *(const uint4*)(vbase + (laneoff + ((IW >> 16) << 6)));           \
  }
#define PCONS(C0, C1, WW)                                                  \
  {                                                                        \
    unsigned int wr0 = WW.x >> sh, wr1 = WW.y >> sh;                       \
    MIX(acc[0], C0.x, wr0, 0); MIX(acc[1], C0.x, wr0, 1);                  \
    MIX(acc[2], C0.y, wr0, 0); MIX(acc[3], C0.y, wr0, 1);                  \
    MIX(acc[4], C0.z, wr0, 0); MIX(acc[5], C0.z, wr0, 1);                  \
    MIX(acc[6], C0.w, wr0, 0); MIX(acc[7], C0.w, wr0, 1);                  \
    MIX(acc[0], C1.x, wr1, 0); MIX(acc[1], C1.x, wr1, 1);                  \
    MIX(acc[2], C1.y, wr1, 0); MIX(acc[3], C1.y, wr1, 1);                  \
    MIX(acc[4], C1.z, wr1, 0); MIX(acc[5], C1.z, wr1, 1);                  \
    MIX(acc[6], C1.w, wr1, 0); MIX(acc[7], C1.w, wr1, 1);                  \
  }

    float acc[8];
#pragma unroll
    for (int j = 0; j < 8; ++j) acc[j] = 0.f;

    unsigned int iwA0, iwA1, iwB0, iwB1;
    uint2 wwA0, wwA1, wwB0, wwB1;
    uint4 A00, A01, A10, A11, B00, B01, B10, B11;
    PLOAD(A00, A01, iwA0, wwA0, 0);
    PLOAD(A10, A11, iwA1, wwA1, 1);
#pragma unroll
    for (int it = 0; it < 8; ++it) {
      if (it & 1) {
        if (it < 7) {
          PLOAD(A00, A01, iwA0, wwA0, 2 * it + 2);
          PLOAD(A10, A11, iwA1, wwA1, 2 * it + 3);
        }
        __builtin_amdgcn_sched_barrier(0);
        PCONS(B00, B01, wwB0);
        PCONS(B10, B11, wwB1);
      } else {
        if (it < 7) {
          PLOAD(B00, B01, iwB0, wwB0, 2 * it + 2);
          PLOAD(B10, B11, iwB1, wwB1, 2 * it + 3);
        }
        __builtin_amdgcn_sched_barrier(0);
        PCONS(A00, A01, wwA0);
        PCONS(A10, A11, wwA1);
      }
    }
#undef PLOAD
#undef PCONS

    // combine slot halves: lanes tp and tp^4 hold same dims, diff pixel
#pragma unroll
    for (int j = 0; j < 8; ++j) acc[j] += __shfl_xor(acc[j], 4, 64);

    const int qg = qb * QPB + q;
    if (((lane & 4) == 0) && qg < LQ) {
      uint4 pk;
      pk.x = (unsigned int)f2bf(acc[0]) | ((unsigned int)f2bf(acc[1]) << 16);
      pk.y = (unsigned int)f2bf(acc[2]) | ((unsigned int)f2bf(acc[3]) << 16);
      pk.z = (unsigned int)f2bf(acc[4]) | ((unsigned int)f2bf(acc[5]) << 16);
      pk.w = (unsigned int)f2bf(acc[6]) | ((unsigned int)f2bf(acc[7]) << 16);
      *(uint4*)(o_out + ((size_t)b * LQ + qg) * EMBED + h * HEAD_DIM +
                (tp & 3) * 8) = pk;
    }
  }
}

// ---------------------------------------------------------------------------
extern "C" void kernel_launch(void* const* d_in, const int* in_sizes, int n_in,
                              void* d_out, int out_size, void* d_ws,
                              size_t ws_size, hipStream_t stream) {
  const float* query = (const float*)d_in[0];
  const float* refpts = (const float*)d_in[1];
  const float* value = (const float*)d_in[2];
  const uint8_t* mask = (const uint8_t*)d_in[3];
  // d_in[4] = spatial_shapes (hardcoded: {100,100},{50,50},{25,25},{13,13})
  const float* W_off = (const float*)d_in[5];
  const float* b_off = (const float*)d_in[6];
  const float* W_attn = (const float*)d_in[7];
  const float* b_attn = (const float*)d_in[8];
  const float* W_val = (const float*)d_in[9];
  const float* b_val = (const float*)d_in[10];
  const float* W_out = (const float*)d_in[11];
  const float* b_out = (const float*)d_in[12];
  float* out = (float*)d_out;

  // ws layout (bytes); o_ws aliases vbf (dead after gemm_fused01)
  char* ws = (char*)d_ws;
  unsigned short* vh_ws = (unsigned short*)ws;  // f16 [8][26588][32] = 13,613,056
  unsigned short* oah_ws =
      (unsigned short*)(ws + 13613056);  // bf16 [8][26588][48] = 20,419,584
  unsigned short* vbf_ws =
      (unsigned short*)(ws + 34032640);  // bf16 [26588][256] = 13,613,056
  unsigned short* qbf_ws =
      (unsigned short*)(ws + 47645696);  // bf16 [26588][256] = 13,613,056
  unsigned short* wt_val =
      (unsigned short*)(ws + 61258752);            // 131072 B
  unsigned short* wt_oa = wt_val + 256 * 256;      // 196608 B
  unsigned short* wt_out = wt_oa + 384 * 256;      // 131072 B
  unsigned short* o_ws = vbf_ws;  // alias: vbf dead once fused01 completes

  prep_wt_kernel<<<896, 256, 0, stream>>>(W_val, W_off, W_attn, W_out, wt_val,
                                          wt_oa, wt_out);

  // pre-convert A matrices to bf16 (identical rounding to in-GEMM f2bf)
  const int N8 = M_ROWS * EMBED / 8;  // 850,816
  conv_bf16_kernel<<<dim3((N8 + 255) / 256, 2), 256, 0, stream>>>(
      value, query, vbf_ws, qbf_ws, N8);

  const int RB = (M_ROWS + 127) / 128;  // 208 row blocks
  // fused, grid TRANSPOSED (strip fastest): co-dispatched blocks share the
  // same 128-row A slice -> A read once from HBM/L3, 9x from L2.
  gemm_fused01_kernel<<<dim3(10, RB), 256, 0, stream>>>(
      vbf_ws, qbf_ws, wt_val, wt_oa, b_val, b_off, b_attn, mask, vh_ws,
      oah_ws, M_ROWS);

  dim3 g2((LQ + QPB - 1) / QPB, HEADS, BS);  // (416, 8, 2)
  gather_kernel<<<g2, 256, 0, stream>>>(refpts, (const __half*)vh_ws, oah_ws,
                                        o_ws);

  // out = o @ W_out + b_out -> f32 (grid transposed likewise)
  gemm_out_kernel<<<dim3(4, RB), 256, 0, stream>>>(o_ws, wt_out, b_out, out,
                                                   M_ROWS);
}

// Round 21
// 117.320 us; speedup vs baseline: 1.0395x; 1.0395x over previous
//
#include <hip/hip_runtime.h>
#include <hip/hip_bf16.h>
#include <hip/hip_fp16.h>
#include <stdint.h>

#define EMBED 256
#define HEADS 8
#define LEVELS 4
#define POINTS 4
#define HEAD_DIM 32
#define BS 2
#define LV_TOTAL 13294
#define LQ LV_TOTAL
#define TP 128 /* HEADS*LEVELS*POINTS */
#define M_ROWS (BS * LV_TOTAL) /* 26588 */
#define QPB 32 /* queries per gather block (1 head per block) */

typedef __attribute__((ext_vector_type(8))) short bf16x8;
typedef __attribute__((ext_vector_type(4))) float f32x4;

static __device__ __forceinline__ unsigned short f2bf(float x) {
  __hip_bfloat16 h = __float2bfloat16(x);
  return *reinterpret_cast<unsigned short*>(&h);
}
static __device__ __forceinline__ float bf2f(unsigned short u) {
  return __uint_as_float(((unsigned int)u) << 16);
}
static __device__ __forceinline__ unsigned short f2hbits(float x) {
  __half h = __float2half(x);
  return *reinterpret_cast<unsigned short*>(&h);
}

// v_fma_mix_f32: acc(f32) += f16(sel vs of pk) * f16(low half of w)
#define MIX(acc, pk, w, vs)                                              \
  asm("v_fma_mix_f32 %0, %1, %2, %0 op_sel:[" #vs                        \
      ",0,0] op_sel_hi:[1,1,0]"                                          \
      : "+v"(acc)                                                        \
      : "v"(pk), "v"(w))

// ---------------------------------------------------------------------------
// prep_wt: transpose + convert all weight matrices to bf16 WT[n][k] layout.
// ---------------------------------------------------------------------------
__global__ __launch_bounds__(256) void prep_wt_kernel(
    const float* __restrict__ W_val, const float* __restrict__ W_off,
    const float* __restrict__ W_attn, const float* __restrict__ W_out,
    unsigned short* __restrict__ WT_val, unsigned short* __restrict__ WT_oa,
    unsigned short* __restrict__ WT_out) {
  const int bid = blockIdx.x;
  const int k = threadIdx.x;  // 0..255
  const float* src;
  unsigned short* dst;
  int n, N_src;
  if (bid < 256) {
    src = W_val; dst = WT_val; n = bid; N_src = 256;
  } else if (bid < 512) {
    src = W_off; dst = WT_oa; n = bid - 256; N_src = 256;
  } else if (bid < 640) {
    src = W_attn; dst = WT_oa + 256 * 256; n = bid - 512; N_src = 128;
  } else {
    src = W_out; dst = WT_out; n = bid - 640; N_src = 256;
  }
  dst[n * 256 + k] = f2bf(src[(size_t)k * N_src + n]);
}

// ---------------------------------------------------------------------------
// conv_bf16 (dual): f32 -> bf16 for value (y=0) and query (y=1), 8 elem/thr.
// ---------------------------------------------------------------------------
__global__ __launch_bounds__(256) void conv_bf16_kernel(
    const float* __restrict__ value, const float* __restrict__ query,
    unsigned short* __restrict__ vbf, unsigned short* __restrict__ qbf,
    int n8) {
  int i = blockIdx.x * 256 + threadIdx.x;
  const float* in = blockIdx.y ? query : value;
  unsigned short* out = blockIdx.y ? qbf : vbf;
  if (i < n8) {
    float4 p0 = *(const float4*)(in + (size_t)i * 8);
    float4 p1 = *(const float4*)(in + (size_t)i * 8 + 4);
    uint4 o;
    o.x = (unsigned int)f2bf(p0.x) | ((unsigned int)f2bf(p0.y) << 16);
    o.y = (unsigned int)f2bf(p0.z) | ((unsigned int)f2bf(p0.w) << 16);
    o.z = (unsigned int)f2bf(p1.x) | ((unsigned int)f2bf(p1.y) << 16);
    o.w = (unsigned int)f2bf(p1.z) | ((unsigned int)f2bf(p1.w) << 16);
    *(uint4*)(out + (size_t)i * 8) = o;
  }
}

// ---------------------------------------------------------------------------
// Round-9 GEMM body (PROVEN): one 64-col strip x 128 rows; B panel (32 KB)
// in LDS w/ XOR swizzle; per kk: 2 bf16 A-frags, 4 ds_read_b128, 8 MFMA.
// Grid (RB, strips) — round-19 proven order (rows fastest).
// OUT_MODE: 0=f32, 1=bf16, 2=f16 head-major vh, 3=bf16 head-major oa_h.
// ---------------------------------------------------------------------------
template <int NTOT, int OUT_MODE, bool MASKED, bool SPLIT_BIAS>
static __device__ __forceinline__ void gemm_body(
    unsigned short* bpanel, const unsigned short* __restrict__ Ab,
    const unsigned short* __restrict__ BT, const float* __restrict__ bias0,
    const float* __restrict__ bias1, const uint8_t* __restrict__ mask,
    void* __restrict__ Cv, int M, int strip) {
  const int tid = threadIdx.x;
  const int col0 = strip * 64;

  // ---- stage B panel (64 cols x 256 k, bf16), XOR-swizzled ----
#pragma unroll
  for (int it = 0; it < 8; ++it) {
    int c = it * 256 + tid;  // chunk id 0..2047 (16B chunks)
    int col = c >> 5;        // 0..63
    int kc = c & 31;         // 16B chunk within the col's 512B row
    uint4 vdat = *(const uint4*)(BT + ((size_t)(col0 + col)) * 256 + kc * 8);
    int byteoff = (col << 9) + ((kc << 4) ^ ((col & 7) << 4));
    *(uint4*)((char*)bpanel + byteoff) = vdat;
  }
  __syncthreads();

  const int wave = tid >> 6;
  const int lane = tid & 63;
  const int lr = lane & 15;
  const int kq = lane >> 4;  // 0..3
  const int rowW = blockIdx.x * 128 + wave * 16;
  const int ar0 = min(rowW + lr, M - 1);
  const int ar1 = min(rowW + 64 + lr, M - 1);

  f32x4 acc[2][4];
#pragma unroll
  for (int ri = 0; ri < 2; ++ri)
#pragma unroll
    for (int c = 0; c < 4; ++c) acc[ri][c] = (f32x4){0.f, 0.f, 0.f, 0.f};

#pragma unroll
  for (int kk = 0; kk < 8; ++kk) {
    const int k0 = kk * 32 + kq * 8;
    bf16x8 a0 = *(const bf16x8*)(Ab + (size_t)ar0 * 256 + k0);
    bf16x8 a1 = *(const bf16x8*)(Ab + (size_t)ar1 * 256 + k0);
#pragma unroll
    for (int c = 0; c < 4; ++c) {
      const int col = c * 16 + lr;
      const int byteoff = (col << 9) + (((k0 * 2)) ^ ((col & 7) << 4));
      bf16x8 bfrag = *(const bf16x8*)((const char*)bpanel + byteoff);
      acc[0][c] =
          __builtin_amdgcn_mfma_f32_16x16x32_bf16(a0, bfrag, acc[0][c], 0, 0, 0);
      acc[1][c] =
          __builtin_amdgcn_mfma_f32_16x16x32_bf16(a1, bfrag, acc[1][c], 0, 0, 0);
    }
  }

  // epilogue: D col = lane&15, row = (lane>>4)*4 + i   [m89-verified]
#pragma unroll
  for (int c = 0; c < 4; ++c) {
    const int col = col0 + c * 16 + lr;
    float bv;
    if constexpr (SPLIT_BIAS)
      bv = (col < 256) ? bias0[col] : bias1[col - 256];
    else
      bv = bias0[col];
#pragma unroll
    for (int ri = 0; ri < 2; ++ri) {
#pragma unroll
      for (int i = 0; i < 4; ++i) {
        const int row = rowW + ri * 64 + kq * 4 + i;
        if (row < M) {
          float o = acc[ri][c][i] + bv;
          if constexpr (MASKED) {
            if (mask[row]) o = 0.f;
          }
          if constexpr (OUT_MODE == 0) {
            ((float*)Cv)[(size_t)row * NTOT + col] = o;
          } else if constexpr (OUT_MODE == 1) {
            ((unsigned short*)Cv)[(size_t)row * NTOT + col] = f2bf(o);
          } else if constexpr (OUT_MODE == 2) {
            ((unsigned short*)Cv)[(size_t)(col >> 5) * ((size_t)M * 32) +
                                  (size_t)row * 32 + (col & 31)] = f2hbits(o);
          } else {
            // head-major oa: [h][row][48], off cols 0..31, attn cols 32..47
            int hh, w_;
            if (col < 256) { hh = col >> 5; w_ = col & 31; }
            else { int c2 = col - 256; hh = c2 >> 4; w_ = 32 + (c2 & 15); }
            ((unsigned short*)Cv)[((size_t)hh * M + row) * 48 + w_] = f2bf(o);
          }
        }
      }
    }
  }
}

// fat kernel: strips 0-3 = vproj (value_bf -> f16 head-major vh),
//             strips 4-9 = oa (query_bf -> bf16 head-major oa_h)
__global__ __launch_bounds__(256) void gemm_fused01_kernel(
    const unsigned short* __restrict__ value_bf,
    const unsigned short* __restrict__ query_bf,
    const unsigned short* __restrict__ wt_val,
    const unsigned short* __restrict__ wt_oa, const float* __restrict__ b_val,
    const float* __restrict__ b_off, const float* __restrict__ b_attn,
    const uint8_t* __restrict__ mask, unsigned short* __restrict__ vh,
    unsigned short* __restrict__ oah, int M) {
  __shared__ uint4 bpanel4[2048];  // 32 KB
  unsigned short* bp = (unsigned short*)bpanel4;
  if (blockIdx.y < 4)
    gemm_body<256, 2, true, false>(bp, value_bf, wt_val, b_val, nullptr, mask,
                                   vh, M, blockIdx.y);
  else
    gemm_body<384, 3, false, true>(bp, query_bf, wt_oa, b_off, b_attn,
                                   nullptr, oah, M, blockIdx.y - 4);
}

__global__ __launch_bounds__(256) void gemm_out_kernel(
    const unsigned short* __restrict__ o_in,
    const unsigned short* __restrict__ wt_out, const float* __restrict__ b_out,
    float* __restrict__ out, int M) {
  __shared__ uint4 bpanel4[2048];
  unsigned short* bp = (unsigned short*)bpanel4;
  gemm_body<256, 0, false, false>(bp, o_in, wt_out, b_out, nullptr, nullptr,
                                  out, M, blockIdx.y);
}

// ---------------------------------------------------------------------------
// gather_kernel (HEAD-PARTITIONED + depth-3 rotating pipeline): block = 32
// queries x 1 head x 1 batch, grid (416, 8, 2).  vh slice L2-resident.
// 3-slot rotation: samples issued 3 PCONS-blocks (~48 MIX) ahead; slot index
// compile-time under full unroll; VGPR stays < 64 (acc[8] + 3x10 slot regs).
// ---------------------------------------------------------------------------
__global__ __launch_bounds__(256) void gather_kernel(
    const float* __restrict__ refpts,
    const __half* __restrict__ vh,           // f16 head-major [8][M][32]
    const unsigned short* __restrict__ oah,  // bf16 head-major [8][M][48]
    unsigned short* __restrict__ o_out) {    // bf16 (BS*LQ, 256)
  __shared__ unsigned short oas[QPB * 48];    // 3 KB raw bf16 [q][48]
  __shared__ float attn_s[QPB][16];           // 2 KB
  __shared__ float ref_s[QPB][LEVELS][2];     // 1 KB
  __shared__ unsigned int meta_idx[QPB][16];  // 2 KB
  __shared__ uint2 meta_w[QPB][16];           // 4 KB

  const int qb = blockIdx.x;  // 0..415
  const int h = blockIdx.y;   // 0..7
  const int b = blockIdx.z;   // 0..1
  const int tid = threadIdx.x;

  // ---- stage oa head-slice: 32 rows x 48 shorts (96 B/row, 6 uint4) ----
  {
    int row = tid >> 3, j = tid & 7;
    if (j < 6) {
      int qg = min(qb * QPB + row, LQ - 1);
      *(uint4*)(oas + row * 48 + j * 8) = *(const uint4*)(
          oah + ((size_t)h * M_ROWS + (size_t)b * LQ + qg) * 48 + j * 8);
    }
  }
  // ---- reference points: 32 q x 8 vals ----
  {
    int q = tid >> 3, rem = tid & 7;
    int qg = min(qb * QPB + q, LQ - 1);
    ref_s[q][rem >> 1][rem & 1] = refpts[((size_t)b * LQ + qg) * 8 + rem];
  }
  __syncthreads();

  // ---- softmax per q over this head's 16 logits (oas cols 32..47) ----
  if (tid < QPB) {
    const unsigned short* arow = oas + tid * 48 + 32;
    float m = bf2f(arow[0]);
#pragma unroll
    for (int i = 1; i < 16; ++i) m = fmaxf(m, bf2f(arow[i]));
    float ssum = 0.f;
#pragma unroll
    for (int i = 0; i < 16; ++i) {
      float e = __expf(bf2f(arow[i]) - m);
      attn_s[tid][i] = e;
      ssum += e;
    }
    float inv = 1.f / ssum;
#pragma unroll
    for (int i = 0; i < 16; ++i) attn_s[tid][i] *= inv;
  }
  __syncthreads();

  // ---- meta precompute: 512 samples (32q x 16), 2 per thread ----
#pragma unroll
  for (int pass = 0; pass < 2; ++pass) {
    const int s = pass * 256 + tid;
    const int q = s >> 4, smp = s & 15;
    const int l = smp >> 2, p = smp & 3;
    const int W = (l == 0) ? 100 : (l == 1) ? 50 : (l == 2) ? 25 : 13;
    const int base = (l == 0) ? 0 : (l == 1) ? 10000 : (l == 2) ? 12500 : 13125;
    const float fW = (float)W;

    float ox = bf2f(oas[q * 48 + l * 8 + p * 2]);
    float oy = bf2f(oas[q * 48 + l * 8 + p * 2 + 1]);
    float rx = ref_s[q][l][0], ry = ref_s[q][l][1];
    float aw = attn_s[q][smp];
    float x = fmaf(rx, fW, ox) - 0.5f;
    float y = fmaf(ry, fW, oy) - 0.5f;  // H == W for all levels
    float x0f = floorf(x), y0f = floorf(y);
    float lw = x - x0f, lh = y - y0f;
    int x0 = (int)x0f, y0 = (int)y0f;
    int x1 = x0 + 1, y1 = y0 + 1;
    int xbase = min(max(x0, 0), W - 2);
    bool x0v = (x0 >= 0) && (x0 < W);
    bool x1v = (x1 >= 0) && (x1 < W);
    float ws0 = ((x0v && x0 == xbase) ? (1.f - lw) : 0.f) +
                ((x1v && x1 == xbase) ? lw : 0.f);
    float ws1 = ((x0v && x0 == xbase + 1) ? (1.f - lw) : 0.f) +
                ((x1v && x1 == xbase + 1) ? lw : 0.f);
    bool y0v = (y0 >= 0) && (y0 < W);
    bool y1v = (y1 >= 0) && (y1 < W);
    int yc0 = min(max(y0, 0), W - 1), yc1 = min(max(y1, 0), W - 1);
    float wy0 = y0v ? (1.f - lh) * aw : 0.f;
    float wy1 = y1v ? lh * aw : 0.f;
    const int posx = smp ^ (q & 7);  // bank swizzle, involution within row
    meta_w[q][posx] = make_uint2(
        (unsigned int)f2hbits(wy0 * ws0) |
            ((unsigned int)f2hbits(wy0 * ws1) << 16),
        (unsigned int)f2hbits(wy1 * ws0) |
            ((unsigned int)f2hbits(wy1 * ws1) << 16));
    meta_idx[q][posx] = (unsigned int)(yc0 * W + xbase + base) |
                        ((unsigned int)(yc1 * W + xbase + base) << 16);
  }
  __syncthreads();

  // ---- gather: lane = ql(8) x tp(8); depth-3 rotation, 16 samples ----
  {
    const int lane = tid & 63;
    const int wave = tid >> 6;
    const int ql = lane >> 3;     // query within wave
    const int q = wave * 8 + ql;  // 0..31 block-local query
    const int tp = lane & 7;      // pair-span octet
    const char* vbase = (const char*)vh +
                        ((size_t)h * M_ROWS + (size_t)b * LV_TOTAL) * 64;
    const unsigned int laneoff =
        (unsigned int)(tp >> 2) * 64 + (unsigned int)(tp & 3) * 16;
    const unsigned int sh = (lane & 4) << 2;  // 0 (slot0) or 16 (slot1)

#define PLOAD(C0, C1, WW, smp)                                             \
  {                                                                        \
    const int pos_ = (smp) ^ ql;                                           \
    unsigned int iw_ = meta_idx[q][pos_];                                  \
    WW = meta_w[q][pos_];                                                  \
    C0 = *(const uint4*)(vbase + (laneoff + ((iw_ & 0xffffu) << 6)));      \
    C1 = *(const uint4*)(vbase + (laneoff + ((iw_ >> 16) << 6)));          \
  }
#define PCONS(C0, C1, WW)                                                  \
  {                                                                        \
    unsigned int wr0 = WW.x >> sh, wr1 = WW.y >> sh;                       \
    MIX(acc[0], C0.x, wr0, 0); MIX(acc[1], C0.x, wr0, 1);                  \
    MIX(acc[2], C0.y, wr0, 0); MIX(acc[3], C0.y, wr0, 1);                  \
    MIX(acc[4], C0.z, wr0, 0); MIX(acc[5], C0.z, wr0, 1);                  \
    MIX(acc[6], C0.w, wr0, 0); MIX(acc[7], C0.w, wr0, 1);                  \
    MIX(acc[0], C1.x, wr1, 0); MIX(acc[1], C1.x, wr1, 1);                  \
    MIX(acc[2], C1.y, wr1, 0); MIX(acc[3], C1.y, wr1, 1);                  \
    MIX(acc[4], C1.z, wr1, 0); MIX(acc[5], C1.z, wr1, 1);                  \
    MIX(acc[6], C1.w, wr1, 0); MIX(acc[7], C1.w, wr1, 1);                  \
  }

    float acc[8];
#pragma unroll
    for (int j = 0; j < 8; ++j) acc[j] = 0.f;

    uint4 Xa0, Xa1, Xb0, Xb1, Xc0, Xc1;
    uint2 Wa, Wb, Wc;
    PLOAD(Xa0, Xa1, Wa, 0);
    PLOAD(Xb0, Xb1, Wb, 1);
    PLOAD(Xc0, Xc1, Wc, 2);
#pragma unroll
    for (int st = 0; st < 16; ++st) {
      if ((st % 3) == 0) {
        __builtin_amdgcn_sched_barrier(0);
        PCONS(Xa0, Xa1, Wa);
        if (st + 3 < 16) PLOAD(Xa0, Xa1, Wa, st + 3);
      } else if ((st % 3) == 1) {
        __builtin_amdgcn_sched_barrier(0);
        PCONS(Xb0, Xb1, Wb);
        if (st + 3 < 16) PLOAD(Xb0, Xb1, Wb, st + 3);
      } else {
        __builtin_amdgcn_sched_barrier(0);
        PCONS(Xc0, Xc1, Wc);
        if (st + 3 < 16) PLOAD(Xc0, Xc1, Wc, st + 3);
      }
    }
#undef PLOAD
#undef PCONS

    // combine slot halves: lanes tp and tp^4 hold same dims, diff pixel
#pragma unroll
    for (int j = 0; j < 8; ++j) acc[j] += __shfl_xor(acc[j], 4, 64);

    const int qg = qb * QPB + q;
    if (((lane & 4) == 0) && qg < LQ) {
      uint4 pk;
      pk.x = (unsigned int)f2bf(acc[0]) | ((unsigned int)f2bf(acc[1]) << 16);
      pk.y = (unsigned int)f2bf(acc[2]) | ((unsigned int)f2bf(acc[3]) << 16);
      pk.z = (unsigned int)f2bf(acc[4]) | ((unsigned int)f2bf(acc[5]) << 16);
      pk.w = (unsigned int)f2bf(acc[6]) | ((unsigned int)f2bf(acc[7]) << 16);
      *(uint4*)(o_out + ((size_t)b * LQ + qg) * EMBED + h * HEAD_DIM +
                (tp & 3) * 8) = pk;
    }
  }
}

// ---------------------------------------------------------------------------
extern "C" void kernel_launch(void* const* d_in, const int* in_sizes, int n_in,
                              void* d_out, int out_size, void* d_ws,
                              size_t ws_size, hipStream_t stream) {
  const float* query = (const float*)d_in[0];
  const float* refpts = (const float*)d_in[1];
  const float* value = (const float*)d_in[2];
  const uint8_t* mask = (const uint8_t*)d_in[3];
  // d_in[4] = spatial_shapes (hardcoded: {100,100},{50,50},{25,25},{13,13})
  const float* W_off = (const float*)d_in[5];
  const float* b_off = (const float*)d_in[6];
  const float* W_attn = (const float*)d_in[7];
  const float* b_attn = (const float*)d_in[8];
  const float* W_val = (const float*)d_in[9];
  const float* b_val = (const float*)d_in[10];
  const float* W_out = (const float*)d_in[11];
  const float* b_out = (const float*)d_in[12];
  float* out = (float*)d_out;

  // ws layout (bytes); o_ws aliases vbf (dead after gemm_fused01)
  char* ws = (char*)d_ws;
  unsigned short* vh_ws = (unsigned short*)ws;  // f16 [8][26588][32] = 13,613,056
  unsigned short* oah_ws =
      (unsigned short*)(ws + 13613056);  // bf16 [8][26588][48] = 20,419,584
  unsigned short* vbf_ws =
      (unsigned short*)(ws + 34032640);  // bf16 [26588][256] = 13,613,056
  unsigned short* qbf_ws =
      (unsigned short*)(ws + 47645696);  // bf16 [26588][256] = 13,613,056
  unsigned short* wt_val =
      (unsigned short*)(ws + 61258752);            // 131072 B
  unsigned short* wt_oa = wt_val + 256 * 256;      // 196608 B
  unsigned short* wt_out = wt_oa + 384 * 256;      // 131072 B
  unsigned short* o_ws = vbf_ws;  // alias: vbf dead once fused01 completes

  prep_wt_kernel<<<896, 256, 0, stream>>>(W_val, W_off, W_attn, W_out, wt_val,
                                          wt_oa, wt_out);

  // pre-convert A matrices to bf16 (identical rounding to in-GEMM f2bf)
  const int N8 = M_ROWS * EMBED / 8;  // 850,816
  conv_bf16_kernel<<<dim3((N8 + 255) / 256, 2), 256, 0, stream>>>(
      value, query, vbf_ws, qbf_ws, N8);

  const int RB = (M_ROWS + 127) / 128;  // 208 row blocks
  // fused: vproj (strips 0-3) + offsets/attn (strips 4-9), bf16 A
  gemm_fused01_kernel<<<dim3(RB, 10), 256, 0, stream>>>(
      vbf_ws, qbf_ws, wt_val, wt_oa, b_val, b_off, b_attn, mask, vh_ws,
      oah_ws, M_ROWS);

  dim3 g2((LQ + QPB - 1) / QPB, HEADS, BS);  // (416, 8, 2)
  gather_kernel<<<g2, 256, 0, stream>>>(refpts, (const __half*)vh_ws, oah_ws,
                                        o_ws);

  // out = o @ W_out + b_out -> f32
  gemm_out_kernel<<<dim3(RB, 4), 256, 0, stream>>>(o_ws, wt_out, b_out, out,
                                                   M_ROWS);
}

// Round 22
// 109.851 us; speedup vs baseline: 1.1102x; 1.0680x over previous
//
#include <hip/hip_runtime.h>
#include <hip/hip_bf16.h>
#include <hip/hip_fp16.h>
#include <stdint.h>

#define EMBED 256
#define HEADS 8
#define LEVELS 4
#define POINTS 4
#define HEAD_DIM 32
#define BS 2
#define LV_TOTAL 13294
#define LQ LV_TOTAL
#define TP 128 /* HEADS*LEVELS*POINTS */
#define M_ROWS (BS * LV_TOTAL) /* 26588 */
#define QPB 32 /* queries per gather block (1 head per block) */
#define QB_N 416 /* ceil(LQ/QPB) */

typedef __attribute__((ext_vector_type(8))) short bf16x8;
typedef __attribute__((ext_vector_type(4))) float f32x4;

static __device__ __forceinline__ unsigned short f2bf(float x) {
  __hip_bfloat16 h = __float2bfloat16(x);
  return *reinterpret_cast<unsigned short*>(&h);
}
static __device__ __forceinline__ float bf2f(unsigned short u) {
  return __uint_as_float(((unsigned int)u) << 16);
}
static __device__ __forceinline__ unsigned short f2hbits(float x) {
  __half h = __float2half(x);
  return *reinterpret_cast<unsigned short*>(&h);
}

// v_fma_mix_f32: acc(f32) += f16(sel vs of pk) * f16(low half of w)
#define MIX(acc, pk, w, vs)                                              \
  asm("v_fma_mix_f32 %0, %1, %2, %0 op_sel:[" #vs                        \
      ",0,0] op_sel_hi:[1,1,0]"                                          \
      : "+v"(acc)                                                        \
      : "v"(pk), "v"(w))

// ---------------------------------------------------------------------------
// prep_wt: transpose + convert all weight matrices to bf16 WT[n][k] layout.
// ---------------------------------------------------------------------------
__global__ __launch_bounds__(256) void prep_wt_kernel(
    const float* __restrict__ W_val, const float* __restrict__ W_off,
    const float* __restrict__ W_attn, const float* __restrict__ W_out,
    unsigned short* __restrict__ WT_val, unsigned short* __restrict__ WT_oa,
    unsigned short* __restrict__ WT_out) {
  const int bid = blockIdx.x;
  const int k = threadIdx.x;  // 0..255
  const float* src;
  unsigned short* dst;
  int n, N_src;
  if (bid < 256) {
    src = W_val; dst = WT_val; n = bid; N_src = 256;
  } else if (bid < 512) {
    src = W_off; dst = WT_oa; n = bid - 256; N_src = 256;
  } else if (bid < 640) {
    src = W_attn; dst = WT_oa + 256 * 256; n = bid - 512; N_src = 128;
  } else {
    src = W_out; dst = WT_out; n = bid - 640; N_src = 256;
  }
  dst[n * 256 + k] = f2bf(src[(size_t)k * N_src + n]);
}

// ---------------------------------------------------------------------------
// conv_bf16 (dual): f32 -> bf16 for value (y=0) and query (y=1), 8 elem/thr.
// ---------------------------------------------------------------------------
__global__ __launch_bounds__(256) void conv_bf16_kernel(
    const float* __restrict__ value, const float* __restrict__ query,
    unsigned short* __restrict__ vbf, unsigned short* __restrict__ qbf,
    int n8) {
  int i = blockIdx.x * 256 + threadIdx.x;
  const float* in = blockIdx.y ? query : value;
  unsigned short* out = blockIdx.y ? qbf : vbf;
  if (i < n8) {
    float4 p0 = *(const float4*)(in + (size_t)i * 8);
    float4 p1 = *(const float4*)(in + (size_t)i * 8 + 4);
    uint4 o;
    o.x = (unsigned int)f2bf(p0.x) | ((unsigned int)f2bf(p0.y) << 16);
    o.y = (unsigned int)f2bf(p0.z) | ((unsigned int)f2bf(p0.w) << 16);
    o.z = (unsigned int)f2bf(p1.x) | ((unsigned int)f2bf(p1.y) << 16);
    o.w = (unsigned int)f2bf(p1.z) | ((unsigned int)f2bf(p1.w) << 16);
    *(uint4*)(out + (size_t)i * 8) = o;
  }
}

// ---------------------------------------------------------------------------
// Round-9 GEMM body (PROVEN): one 64-col strip x 128 rows; B panel (32 KB)
// in LDS w/ XOR swizzle; per kk: 2 bf16 A-frags, 4 ds_read_b128, 8 MFMA.
// Grid (RB, strips) — round-19 proven order (rows fastest).
// OUT_MODE: 0=f32, 1=bf16, 2=f16 head-major vh, 3=bf16 head-major oa_h.
// ---------------------------------------------------------------------------
template <int NTOT, int OUT_MODE, bool MASKED, bool SPLIT_BIAS>
static __device__ __forceinline__ void gemm_body(
    unsigned short* bpanel, const unsigned short* __restrict__ Ab,
    const unsigned short* __restrict__ BT, const float* __restrict__ bias0,
    const float* __restrict__ bias1, const uint8_t* __restrict__ mask,
    void* __restrict__ Cv, int M, int strip) {
  const int tid = threadIdx.x;
  const int col0 = strip * 64;

  // ---- stage B panel (64 cols x 256 k, bf16), XOR-swizzled ----
#pragma unroll
  for (int it = 0; it < 8; ++it) {
    int c = it * 256 + tid;  // chunk id 0..2047 (16B chunks)
    int col = c >> 5;        // 0..63
    int kc = c & 31;         // 16B chunk within the col's 512B row
    uint4 vdat = *(const uint4*)(BT + ((size_t)(col0 + col)) * 256 + kc * 8);
    int byteoff = (col << 9) + ((kc << 4) ^ ((col & 7) << 4));
    *(uint4*)((char*)bpanel + byteoff) = vdat;
  }
  __syncthreads();

  const int wave = tid >> 6;
  const int lane = tid & 63;
  const int lr = lane & 15;
  const int kq = lane >> 4;  // 0..3
  const int rowW = blockIdx.x * 128 + wave * 16;
  const int ar0 = min(rowW + lr, M - 1);
  const int ar1 = min(rowW + 64 + lr, M - 1);

  f32x4 acc[2][4];
#pragma unroll
  for (int ri = 0; ri < 2; ++ri)
#pragma unroll
    for (int c = 0; c < 4; ++c) acc[ri][c] = (f32x4){0.f, 0.f, 0.f, 0.f};

#pragma unroll
  for (int kk = 0; kk < 8; ++kk) {
    const int k0 = kk * 32 + kq * 8;
    bf16x8 a0 = *(const bf16x8*)(Ab + (size_t)ar0 * 256 + k0);
    bf16x8 a1 = *(const bf16x8*)(Ab + (size_t)ar1 * 256 + k0);
#pragma unroll
    for (int c = 0; c < 4; ++c) {
      const int col = c * 16 + lr;
      const int byteoff = (col << 9) + (((k0 * 2)) ^ ((col & 7) << 4));
      bf16x8 bfrag = *(const bf16x8*)((const char*)bpanel + byteoff);
      acc[0][c] =
          __builtin_amdgcn_mfma_f32_16x16x32_bf16(a0, bfrag, acc[0][c], 0, 0, 0);
      acc[1][c] =
          __builtin_amdgcn_mfma_f32_16x16x32_bf16(a1, bfrag, acc[1][c], 0, 0, 0);
    }
  }

  // epilogue: D col = lane&15, row = (lane>>4)*4 + i   [m89-verified]
#pragma unroll
  for (int c = 0; c < 4; ++c) {
    const int col = col0 + c * 16 + lr;
    float bv;
    if constexpr (SPLIT_BIAS)
      bv = (col < 256) ? bias0[col] : bias1[col - 256];
    else
      bv = bias0[col];
#pragma unroll
    for (int ri = 0; ri < 2; ++ri) {
#pragma unroll
      for (int i = 0; i < 4; ++i) {
        const int row = rowW + ri * 64 + kq * 4 + i;
        if (row < M) {
          float o = acc[ri][c][i] + bv;
          if constexpr (MASKED) {
            if (mask[row]) o = 0.f;
          }
          if constexpr (OUT_MODE == 0) {
            ((float*)Cv)[(size_t)row * NTOT + col] = o;
          } else if constexpr (OUT_MODE == 1) {
            ((unsigned short*)Cv)[(size_t)row * NTOT + col] = f2bf(o);
          } else if constexpr (OUT_MODE == 2) {
            ((unsigned short*)Cv)[(size_t)(col >> 5) * ((size_t)M * 32) +
                                  (size_t)row * 32 + (col & 31)] = f2hbits(o);
          } else {
            // head-major oa: [h][row][48], off cols 0..31, attn cols 32..47
            int hh, w_;
            if (col < 256) { hh = col >> 5; w_ = col & 31; }
            else { int c2 = col - 256; hh = c2 >> 4; w_ = 32 + (c2 & 15); }
            ((unsigned short*)Cv)[((size_t)hh * M + row) * 48 + w_] = f2bf(o);
          }
        }
      }
    }
  }
}

// fat kernel: strips 0-3 = vproj (value_bf -> f16 head-major vh),
//             strips 4-9 = oa (query_bf -> bf16 head-major oa_h)
__global__ __launch_bounds__(256) void gemm_fused01_kernel(
    const unsigned short* __restrict__ value_bf,
    const unsigned short* __restrict__ query_bf,
    const unsigned short* __restrict__ wt_val,
    const unsigned short* __restrict__ wt_oa, const float* __restrict__ b_val,
    const float* __restrict__ b_off, const float* __restrict__ b_attn,
    const uint8_t* __restrict__ mask, unsigned short* __restrict__ vh,
    unsigned short* __restrict__ oah, int M) {
  __shared__ uint4 bpanel4[2048];  // 32 KB
  unsigned short* bp = (unsigned short*)bpanel4;
  if (blockIdx.y < 4)
    gemm_body<256, 2, true, false>(bp, value_bf, wt_val, b_val, nullptr, mask,
                                   vh, M, blockIdx.y);
  else
    gemm_body<384, 3, false, true>(bp, query_bf, wt_oa, b_off, b_attn,
                                   nullptr, oah, M, blockIdx.y - 4);
}

__global__ __launch_bounds__(256) void gemm_out_kernel(
    const unsigned short* __restrict__ o_in,
    const unsigned short* __restrict__ wt_out, const float* __restrict__ b_out,
    float* __restrict__ out, int M) {
  __shared__ uint4 bpanel4[2048];
  unsigned short* bp = (unsigned short*)bpanel4;
  gemm_body<256, 0, false, false>(bp, o_in, wt_out, b_out, nullptr, nullptr,
                                  out, M, blockIdx.y);
}

// ---------------------------------------------------------------------------
// gather_kernel (HEAD-PARTITIONED + h->XCD mapping): flat 1D grid 6656.
// h = bid & 7 so (assuming round-robin bid%8 -> XCD dispatch) each XCD owns
// ONE head's two (batch) slices = 1.7 MB, resident in its 4 MB L2 -> vh
// lines fetched from HBM once instead of ~4.4x (round-19/21 FETCH = 60 MB).
// Inner machinery = round-19 PROVEN depth-2 ping-pong + sched_barrier(0).
// ---------------------------------------------------------------------------
__global__ __launch_bounds__(256) void gather_kernel(
    const float* __restrict__ refpts,
    const __half* __restrict__ vh,           // f16 head-major [8][M][32]
    const unsigned short* __restrict__ oah,  // bf16 head-major [8][M][48]
    unsigned short* __restrict__ o_out) {    // bf16 (BS*LQ, 256)
  __shared__ unsigned short oas[QPB * 48];    // 3 KB raw bf16 [q][48]
  __shared__ float attn_s[QPB][16];           // 2 KB
  __shared__ float ref_s[QPB][LEVELS][2];     // 1 KB
  __shared__ unsigned int meta_idx[QPB][16];  // 2 KB
  __shared__ uint2 meta_w[QPB][16];           // 4 KB

  // flat bid -> (h, b, qb): h fastest (XCD-pinned), then qb, then b
  const int bid = blockIdx.x;        // 0..6655
  const int h = bid & 7;             // head -> XCD (round-robin assumption)
  const int rest = bid >> 3;         // 0..831
  const int b = rest / QB_N;         // batch
  const int qb = rest - b * QB_N;    // query block 0..415
  const int tid = threadIdx.x;

  // ---- stage oa head-slice: 32 rows x 48 shorts (96 B/row, 6 uint4) ----
  {
    int row = tid >> 3, j = tid & 7;
    if (j < 6) {
      int qg = min(qb * QPB + row, LQ - 1);
      *(uint4*)(oas + row * 48 + j * 8) = *(const uint4*)(
          oah + ((size_t)h * M_ROWS + (size_t)b * LQ + qg) * 48 + j * 8);
    }
  }
  // ---- reference points: 32 q x 8 vals ----
  {
    int q = tid >> 3, rem = tid & 7;
    int qg = min(qb * QPB + q, LQ - 1);
    ref_s[q][rem >> 1][rem & 1] = refpts[((size_t)b * LQ + qg) * 8 + rem];
  }
  __syncthreads();

  // ---- softmax per q over this head's 16 logits (oas cols 32..47) ----
  if (tid < QPB) {
    const unsigned short* arow = oas + tid * 48 + 32;
    float m = bf2f(arow[0]);
#pragma unroll
    for (int i = 1; i < 16; ++i) m = fmaxf(m, bf2f(arow[i]));
    float ssum = 0.f;
#pragma unroll
    for (int i = 0; i < 16; ++i) {
      float e = __expf(bf2f(arow[i]) - m);
      attn_s[tid][i] = e;
      ssum += e;
    }
    float inv = 1.f / ssum;
#pragma unroll
    for (int i = 0; i < 16; ++i) attn_s[tid][i] *= inv;
  }
  __syncthreads();

  // ---- meta precompute: 512 samples (32q x 16), 2 per thread ----
#pragma unroll
  for (int pass = 0; pass < 2; ++pass) {
    const int s = pass * 256 + tid;
    const int q = s >> 4, smp = s & 15;
    const int l = smp >> 2, p = smp & 3;
    const int W = (l == 0) ? 100 : (l == 1) ? 50 : (l == 2) ? 25 : 13;
    const int base = (l == 0) ? 0 : (l == 1) ? 10000 : (l == 2) ? 12500 : 13125;
    const float fW = (float)W;

    float ox = bf2f(oas[q * 48 + l * 8 + p * 2]);
    float oy = bf2f(oas[q * 48 + l * 8 + p * 2 + 1]);
    float rx = ref_s[q][l][0], ry = ref_s[q][l][1];
    float aw = attn_s[q][smp];
    float x = fmaf(rx, fW, ox) - 0.5f;
    float y = fmaf(ry, fW, oy) - 0.5f;  // H == W for all levels
    float x0f = floorf(x), y0f = floorf(y);
    float lw = x - x0f, lh = y - y0f;
    int x0 = (int)x0f, y0 = (int)y0f;
    int x1 = x0 + 1, y1 = y0 + 1;
    int xbase = min(max(x0, 0), W - 2);
    bool x0v = (x0 >= 0) && (x0 < W);
    bool x1v = (x1 >= 0) && (x1 < W);
    float ws0 = ((x0v && x0 == xbase) ? (1.f - lw) : 0.f) +
                ((x1v && x1 == xbase) ? lw : 0.f);
    float ws1 = ((x0v && x0 == xbase + 1) ? (1.f - lw) : 0.f) +
                ((x1v && x1 == xbase + 1) ? lw : 0.f);
    bool y0v = (y0 >= 0) && (y0 < W);
    bool y1v = (y1 >= 0) && (y1 < W);
    int yc0 = min(max(y0, 0), W - 1), yc1 = min(max(y1, 0), W - 1);
    float wy0 = y0v ? (1.f - lh) * aw : 0.f;
    float wy1 = y1v ? lh * aw : 0.f;
    const int posx = smp ^ (q & 7);  // bank swizzle, involution within row
    meta_w[q][posx] = make_uint2(
        (unsigned int)f2hbits(wy0 * ws0) |
            ((unsigned int)f2hbits(wy0 * ws1) << 16),
        (unsigned int)f2hbits(wy1 * ws0) |
            ((unsigned int)f2hbits(wy1 * ws1) << 16));
    meta_idx[q][posx] = (unsigned int)(yc0 * W + xbase + base) |
                        ((unsigned int)(yc1 * W + xbase + base) << 16);
  }
  __syncthreads();

  // ---- gather: lane = ql(8) x tp(8); depth-2 ping-pong, 16 samples ----
  {
    const int lane = tid & 63;
    const int wave = tid >> 6;
    const int ql = lane >> 3;     // query within wave
    const int q = wave * 8 + ql;  // 0..31 block-local query
    const int tp = lane & 7;      // pair-span octet
    const char* vbase = (const char*)vh +
                        ((size_t)h * M_ROWS + (size_t)b * LV_TOTAL) * 64;
    const unsigned int laneoff =
        (unsigned int)(tp >> 2) * 64 + (unsigned int)(tp & 3) * 16;
    const unsigned int sh = (lane & 4) << 2;  // 0 (slot0) or 16 (slot1)

#define PLOAD(C0, C1, IW, WW, smp)                                         \
  {                                                                        \
    const int pos_ = (smp) ^ ql;                                           \
    IW = meta_idx[q][pos_];                                                \
    WW = meta_w[q][pos_];                                                  \
    C0 = *(const uint4*)(vbase + (laneoff + ((IW & 0xffffu) << 6)));       \
    C1 = *(const uint4*)(vbase + (laneoff + ((IW >> 16) << 6)));           \
  }
#define PCONS(C0, C1, WW)                                                  \
  {                                                                        \
    unsigned int wr0 = WW.x >> sh, wr1 = WW.y >> sh;                       \
    MIX(acc[0], C0.x, wr0, 0); MIX(acc[1], C0.x, wr0, 1);                  \
    MIX(acc[2], C0.y, wr0, 0); MIX(acc[3], C0.y, wr0, 1);                  \
    MIX(acc[4], C0.z, wr0, 0); MIX(acc[5], C0.z, wr0, 1);                  \
    MIX(acc[6], C0.w, wr0, 0); MIX(acc[7], C0.w, wr0, 1);                  \
    MIX(acc[0], C1.x, wr1, 0); MIX(acc[1], C1.x, wr1, 1);                  \
    MIX(acc[2], C1.y, wr1, 0); MIX(acc[3], C1.y, wr1, 1);                  \
    MIX(acc[4], C1.z, wr1, 0); MIX(acc[5], C1.z, wr1, 1);                  \
    MIX(acc[6], C1.w, wr1, 0); MIX(acc[7], C1.w, wr1, 1);                  \
  }

    float acc[8];
#pragma unroll
    for (int j = 0; j < 8; ++j) acc[j] = 0.f;

    unsigned int iwA0, iwA1, iwB0, iwB1;
    uint2 wwA0, wwA1, wwB0, wwB1;
    uint4 A00, A01, A10, A11, B00, B01, B10, B11;
    PLOAD(A00, A01, iwA0, wwA0, 0);
    PLOAD(A10, A11, iwA1, wwA1, 1);
#pragma unroll
    for (int it = 0; it < 8; ++it) {
      if (it & 1) {
        if (it < 7) {
          PLOAD(A00, A01, iwA0, wwA0, 2 * it + 2);
          PLOAD(A10, A11, iwA1, wwA1, 2 * it + 3);
        }
        __builtin_amdgcn_sched_barrier(0);
        PCONS(B00, B01, wwB0);
        PCONS(B10, B11, wwB1);
      } else {
        if (it < 7) {
          PLOAD(B00, B01, iwB0, wwB0, 2 * it + 2);
          PLOAD(B10, B11, iwB1, wwB1, 2 * it + 3);
        }
        __builtin_amdgcn_sched_barrier(0);
        PCONS(A00, A01, wwA0);
        PCONS(A10, A11, wwA1);
      }
    }
#undef PLOAD
#undef PCONS

    // combine slot halves: lanes tp and tp^4 hold same dims, diff pixel
#pragma unroll
    for (int j = 0; j < 8; ++j) acc[j] += __shfl_xor(acc[j], 4, 64);

    const int qg = qb * QPB + q;
    if (((lane & 4) == 0) && qg < LQ) {
      uint4 pk;
      pk.x = (unsigned int)f2bf(acc[0]) | ((unsigned int)f2bf(acc[1]) << 16);
      pk.y = (unsigned int)f2bf(acc[2]) | ((unsigned int)f2bf(acc[3]) << 16);
      pk.z = (unsigned int)f2bf(acc[4]) | ((unsigned int)f2bf(acc[5]) << 16);
      pk.w = (unsigned int)f2bf(acc[6]) | ((unsigned int)f2bf(acc[7]) << 16);
      *(uint4*)(o_out + ((size_t)b * LQ + qg) * EMBED + h * HEAD_DIM +
                (tp & 3) * 8) = pk;
    }
  }
}

// ---------------------------------------------------------------------------
extern "C" void kernel_launch(void* const* d_in, const int* in_sizes, int n_in,
                              void* d_out, int out_size, void* d_ws,
                              size_t ws_size, hipStream_t stream) {
  const float* query = (const float*)d_in[0];
  const float* refpts = (const float*)d_in[1];
  const float* value = (const float*)d_in[2];
  const uint8_t* mask = (const uint8_t*)d_in[3];
  // d_in[4] = spatial_shapes (hardcoded: {100,100},{50,50},{25,25},{13,13})
  const float* W_off = (const float*)d_in[5];
  const float* b_off = (const float*)d_in[6];
  const float* W_attn = (const float*)d_in[7];
  const float* b_attn = (const float*)d_in[8];
  const float* W_val = (const float*)d_in[9];
  const float* b_val = (const float*)d_in[10];
  const float* W_out = (const float*)d_in[11];
  const float* b_out = (const float*)d_in[12];
  float* out = (float*)d_out;

  // ws layout (bytes); o_ws aliases vbf (dead after gemm_fused01)
  char* ws = (char*)d_ws;
  unsigned short* vh_ws = (unsigned short*)ws;  // f16 [8][26588][32] = 13,613,056
  unsigned short* oah_ws =
      (unsigned short*)(ws + 13613056);  // bf16 [8][26588][48] = 20,419,584
  unsigned short* vbf_ws =
      (unsigned short*)(ws + 34032640);  // bf16 [26588][256] = 13,613,056
  unsigned short* qbf_ws =
      (unsigned short*)(ws + 47645696);  // bf16 [26588][256] = 13,613,056
  unsigned short* wt_val =
      (unsigned short*)(ws + 61258752);            // 131072 B
  unsigned short* wt_oa = wt_val + 256 * 256;      // 196608 B
  unsigned short* wt_out = wt_oa + 384 * 256;      // 131072 B
  unsigned short* o_ws = vbf_ws;  // alias: vbf dead once fused01 completes

  prep_wt_kernel<<<896, 256, 0, stream>>>(W_val, W_off, W_attn, W_out, wt_val,
                                          wt_oa, wt_out);

  // pre-convert A matrices to bf16 (identical rounding to in-GEMM f2bf)
  const int N8 = M_ROWS * EMBED / 8;  // 850,816
  conv_bf16_kernel<<<dim3((N8 + 255) / 256, 2), 256, 0, stream>>>(
      value, query, vbf_ws, qbf_ws, N8);

  const int RB = (M_ROWS + 127) / 128;  // 208 row blocks
  // fused: vproj (strips 0-3) + offsets/attn (strips 4-9), bf16 A
  gemm_fused01_kernel<<<dim3(RB, 10), 256, 0, stream>>>(
      vbf_ws, qbf_ws, wt_val, wt_oa, b_val, b_off, b_attn, mask, vh_ws,
      oah_ws, M_ROWS);

  // flat 1D grid: h = bid&7 -> XCD-pinned head slices
  gather_kernel<<<QB_N * HEADS * BS, 256, 0, stream>>>(
      refpts, (const __half*)vh_ws, oah_ws, o_ws);

  // out = o @ W_out + b_out -> f32
  gemm_out_kernel<<<dim3(RB, 4), 256, 0, stream>>>(o_ws, wt_out, b_out, out,
                                                   M_ROWS);
}

// Round 23
// 109.007 us; speedup vs baseline: 1.1188x; 1.0077x over previous
//
#include <hip/hip_runtime.h>
#include <hip/hip_bf16.h>
#include <hip/hip_fp16.h>
#include <stdint.h>

#define EMBED 256
#define HEADS 8
#define LEVELS 4
#define POINTS 4
#define HEAD_DIM 32
#define BS 2
#define LV_TOTAL 13294
#define LQ LV_TOTAL
#define TP 128 /* HEADS*LEVELS*POINTS */
#define M_ROWS (BS * LV_TOTAL) /* 26588 */
#define QPB 32 /* queries per gather block (1 head per block) */
#define QB_N 416 /* ceil(LQ/QPB) */
#define RB_N 208 /* ceil(M_ROWS/128) = 8*26, XCD-chunkable */

typedef __attribute__((ext_vector_type(8))) short bf16x8;
typedef __attribute__((ext_vector_type(4))) float f32x4;

static __device__ __forceinline__ unsigned short f2bf(float x) {
  __hip_bfloat16 h = __float2bfloat16(x);
  return *reinterpret_cast<unsigned short*>(&h);
}
static __device__ __forceinline__ float bf2f(unsigned short u) {
  return __uint_as_float(((unsigned int)u) << 16);
}
static __device__ __forceinline__ unsigned short f2hbits(float x) {
  __half h = __float2half(x);
  return *reinterpret_cast<unsigned short*>(&h);
}

// v_fma_mix_f32: acc(f32) += f16(sel vs of pk) * f16(low half of w)
#define MIX(acc, pk, w, vs)                                              \
  asm("v_fma_mix_f32 %0, %1, %2, %0 op_sel:[" #vs                        \
      ",0,0] op_sel_hi:[1,1,0]"                                          \
      : "+v"(acc)                                                        \
      : "v"(pk), "v"(w))

// ---------------------------------------------------------------------------
// prep_wt: transpose + convert all weight matrices to bf16 WT[n][k] layout.
// ---------------------------------------------------------------------------
__global__ __launch_bounds__(256) void prep_wt_kernel(
    const float* __restrict__ W_val, const float* __restrict__ W_off,
    const float* __restrict__ W_attn, const float* __restrict__ W_out,
    unsigned short* __restrict__ WT_val, unsigned short* __restrict__ WT_oa,
    unsigned short* __restrict__ WT_out) {
  const int bid = blockIdx.x;
  const int k = threadIdx.x;  // 0..255
  const float* src;
  unsigned short* dst;
  int n, N_src;
  if (bid < 256) {
    src = W_val; dst = WT_val; n = bid; N_src = 256;
  } else if (bid < 512) {
    src = W_off; dst = WT_oa; n = bid - 256; N_src = 256;
  } else if (bid < 640) {
    src = W_attn; dst = WT_oa + 256 * 256; n = bid - 512; N_src = 128;
  } else {
    src = W_out; dst = WT_out; n = bid - 640; N_src = 256;
  }
  dst[n * 256 + k] = f2bf(src[(size_t)k * N_src + n]);
}

// ---------------------------------------------------------------------------
// conv_bf16 (dual): f32 -> bf16 for value (y=0) and query (y=1), 8 elem/thr.
// ---------------------------------------------------------------------------
__global__ __launch_bounds__(256) void conv_bf16_kernel(
    const float* __restrict__ value, const float* __restrict__ query,
    unsigned short* __restrict__ vbf, unsigned short* __restrict__ qbf,
    int n8) {
  int i = blockIdx.x * 256 + threadIdx.x;
  const float* in = blockIdx.y ? query : value;
  unsigned short* out = blockIdx.y ? qbf : vbf;
  if (i < n8) {
    float4 p0 = *(const float4*)(in + (size_t)i * 8);
    float4 p1 = *(const float4*)(in + (size_t)i * 8 + 4);
    uint4 o;
    o.x = (unsigned int)f2bf(p0.x) | ((unsigned int)f2bf(p0.y) << 16);
    o.y = (unsigned int)f2bf(p0.z) | ((unsigned int)f2bf(p0.w) << 16);
    o.z = (unsigned int)f2bf(p1.x) | ((unsigned int)f2bf(p1.y) << 16);
    o.w = (unsigned int)f2bf(p1.z) | ((unsigned int)f2bf(p1.w) << 16);
    *(uint4*)(out + (size_t)i * 8) = o;
  }
}

// ---------------------------------------------------------------------------
// Round-9 GEMM body (PROVEN): one 64-col strip x 128 rows; B panel (32 KB)
// in LDS w/ XOR swizzle; per kk: 2 bf16 A-frags, 4 ds_read_b128, 8 MFMA.
// (strip, rowblk) passed explicitly for XCD-chunked flat grids.
// OUT_MODE: 0=f32, 1=bf16, 2=f16 head-major vh, 3=bf16 head-major oa_h.
// ---------------------------------------------------------------------------
template <int NTOT, int OUT_MODE, bool MASKED, bool SPLIT_BIAS>
static __device__ __forceinline__ void gemm_body(
    unsigned short* bpanel, const unsigned short* __restrict__ Ab,
    const unsigned short* __restrict__ BT, const float* __restrict__ bias0,
    const float* __restrict__ bias1, const uint8_t* __restrict__ mask,
    void* __restrict__ Cv, int M, int strip, int rowblk) {
  const int tid = threadIdx.x;
  const int col0 = strip * 64;

  // ---- stage B panel (64 cols x 256 k, bf16), XOR-swizzled ----
#pragma unroll
  for (int it = 0; it < 8; ++it) {
    int c = it * 256 + tid;  // chunk id 0..2047 (16B chunks)
    int col = c >> 5;        // 0..63
    int kc = c & 31;         // 16B chunk within the col's 512B row
    uint4 vdat = *(const uint4*)(BT + ((size_t)(col0 + col)) * 256 + kc * 8);
    int byteoff = (col << 9) + ((kc << 4) ^ ((col & 7) << 4));
    *(uint4*)((char*)bpanel + byteoff) = vdat;
  }
  __syncthreads();

  const int wave = tid >> 6;
  const int lane = tid & 63;
  const int lr = lane & 15;
  const int kq = lane >> 4;  // 0..3
  const int rowW = rowblk * 128 + wave * 16;
  const int ar0 = min(rowW + lr, M - 1);
  const int ar1 = min(rowW + 64 + lr, M - 1);

  f32x4 acc[2][4];
#pragma unroll
  for (int ri = 0; ri < 2; ++ri)
#pragma unroll
    for (int c = 0; c < 4; ++c) acc[ri][c] = (f32x4){0.f, 0.f, 0.f, 0.f};

#pragma unroll
  for (int kk = 0; kk < 8; ++kk) {
    const int k0 = kk * 32 + kq * 8;
    bf16x8 a0 = *(const bf16x8*)(Ab + (size_t)ar0 * 256 + k0);
    bf16x8 a1 = *(const bf16x8*)(Ab + (size_t)ar1 * 256 + k0);
#pragma unroll
    for (int c = 0; c < 4; ++c) {
      const int col = c * 16 + lr;
      const int byteoff = (col << 9) + (((k0 * 2)) ^ ((col & 7) << 4));
      bf16x8 bfrag = *(const bf16x8*)((const char*)bpanel + byteoff);
      acc[0][c] =
          __builtin_amdgcn_mfma_f32_16x16x32_bf16(a0, bfrag, acc[0][c], 0, 0, 0);
      acc[1][c] =
          __builtin_amdgcn_mfma_f32_16x16x32_bf16(a1, bfrag, acc[1][c], 0, 0, 0);
    }
  }

  // epilogue: D col = lane&15, row = (lane>>4)*4 + i   [m89-verified]
#pragma unroll
  for (int c = 0; c < 4; ++c) {
    const int col = col0 + c * 16 + lr;
    float bv;
    if constexpr (SPLIT_BIAS)
      bv = (col < 256) ? bias0[col] : bias1[col - 256];
    else
      bv = bias0[col];
#pragma unroll
    for (int ri = 0; ri < 2; ++ri) {
#pragma unroll
      for (int i = 0; i < 4; ++i) {
        const int row = rowW + ri * 64 + kq * 4 + i;
        if (row < M) {
          float o = acc[ri][c][i] + bv;
          if constexpr (MASKED) {
            if (mask[row]) o = 0.f;
          }
          if constexpr (OUT_MODE == 0) {
            ((float*)Cv)[(size_t)row * NTOT + col] = o;
          } else if constexpr (OUT_MODE == 1) {
            ((unsigned short*)Cv)[(size_t)row * NTOT + col] = f2bf(o);
          } else if constexpr (OUT_MODE == 2) {
            ((unsigned short*)Cv)[(size_t)(col >> 5) * ((size_t)M * 32) +
                                  (size_t)row * 32 + (col & 31)] = f2hbits(o);
          } else {
            // head-major oa: [h][row][48], off cols 0..31, attn cols 32..47
            int hh, w_;
            if (col < 256) { hh = col >> 5; w_ = col & 31; }
            else { int c2 = col - 256; hh = c2 >> 4; w_ = 32 + (c2 & 15); }
            ((unsigned short*)Cv)[((size_t)hh * M + row) * 48 + w_] = f2bf(o);
          }
        }
      }
    }
  }
}

// fat kernel, flat grid 2080 = 8 XCD-chunks x 26 rowblks x 10 strips.
// xcd = bid&7 (round-robin -> XCD, validated round 22); XCD k owns rowblks
// 26k..26k+25, strips of one rowblk dispatched consecutively -> the 64 KB
// A slice lives in that XCD's L2 and serves all 10 strips (A L3 traffic
// 136 MB -> ~14 MB).  strips 0-3 = vproj, 4-9 = oa.
__global__ __launch_bounds__(256) void gemm_fused01_kernel(
    const unsigned short* __restrict__ value_bf,
    const unsigned short* __restrict__ query_bf,
    const unsigned short* __restrict__ wt_val,
    const unsigned short* __restrict__ wt_oa, const float* __restrict__ b_val,
    const float* __restrict__ b_off, const float* __restrict__ b_attn,
    const uint8_t* __restrict__ mask, unsigned short* __restrict__ vh,
    unsigned short* __restrict__ oah, int M) {
  __shared__ uint4 bpanel4[2048];  // 32 KB
  unsigned short* bp = (unsigned short*)bpanel4;
  const int bid = blockIdx.x;
  const int xcd = bid & 7;
  const int idx = bid >> 3;            // 0..259
  const int rb = xcd * 26 + idx / 10;  // 0..207
  const int strip = idx % 10;
  if (strip < 4)
    gemm_body<256, 2, true, false>(bp, value_bf, wt_val, b_val, nullptr, mask,
                                   vh, M, strip, rb);
  else
    gemm_body<384, 3, false, true>(bp, query_bf, wt_oa, b_off, b_attn,
                                   nullptr, oah, M, strip - 4, rb);
}

// flat grid 832 = 8 x 26 x 4: same XCD-chunked mapping for the o matrix.
__global__ __launch_bounds__(256) void gemm_out_kernel(
    const unsigned short* __restrict__ o_in,
    const unsigned short* __restrict__ wt_out, const float* __restrict__ b_out,
    float* __restrict__ out, int M) {
  __shared__ uint4 bpanel4[2048];
  unsigned short* bp = (unsigned short*)bpanel4;
  const int bid = blockIdx.x;
  const int xcd = bid & 7;
  const int idx = bid >> 3;                // 0..103
  const int rb = xcd * 26 + (idx >> 2);    // 0..207
  const int strip = idx & 3;
  gemm_body<256, 0, false, false>(bp, o_in, wt_out, b_out, nullptr, nullptr,
                                  out, M, strip, rb);
}

// ---------------------------------------------------------------------------
// gather_kernel (HEAD-PARTITIONED + h->XCD mapping, round-22 PROVEN):
// flat 1D grid 6656; h = bid&7 pins each head's 1.7 MB vh slice to one
// XCD's L2 (FETCH 60 -> 20 MB).  Depth-2 ping-pong + sched_barrier(0).
// ---------------------------------------------------------------------------
__global__ __launch_bounds__(256) void gather_kernel(
    const float* __restrict__ refpts,
    const __half* __restrict__ vh,           // f16 head-major [8][M][32]
    const unsigned short* __restrict__ oah,  // bf16 head-major [8][M][48]
    unsigned short* __restrict__ o_out) {    // bf16 (BS*LQ, 256)
  __shared__ unsigned short oas[QPB * 48];    // 3 KB raw bf16 [q][48]
  __shared__ float attn_s[QPB][16];           // 2 KB
  __shared__ float ref_s[QPB][LEVELS][2];     // 1 KB
  __shared__ unsigned int meta_idx[QPB][16];  // 2 KB
  __shared__ uint2 meta_w[QPB][16];           // 4 KB

  // flat bid -> (h, b, qb): h fastest (XCD-pinned), then qb, then b
  const int bid = blockIdx.x;        // 0..6655
  const int h = bid & 7;             // head -> XCD (round-robin, validated)
  const int rest = bid >> 3;         // 0..831
  const int b = rest / QB_N;         // batch
  const int qb = rest - b * QB_N;    // query block 0..415
  const int tid = threadIdx.x;

  // ---- stage oa head-slice: 32 rows x 48 shorts (96 B/row, 6 uint4) ----
  {
    int row = tid >> 3, j = tid & 7;
    if (j < 6) {
      int qg = min(qb * QPB + row, LQ - 1);
      *(uint4*)(oas + row * 48 + j * 8) = *(const uint4*)(
          oah + ((size_t)h * M_ROWS + (size_t)b * LQ + qg) * 48 + j * 8);
    }
  }
  // ---- reference points: 32 q x 8 vals ----
  {
    int q = tid >> 3, rem = tid & 7;
    int qg = min(qb * QPB + q, LQ - 1);
    ref_s[q][rem >> 1][rem & 1] = refpts[((size_t)b * LQ + qg) * 8 + rem];
  }
  __syncthreads();

  // ---- softmax per q over this head's 16 logits (oas cols 32..47) ----
  if (tid < QPB) {
    const unsigned short* arow = oas + tid * 48 + 32;
    float m = bf2f(arow[0]);
#pragma unroll
    for (int i = 1; i < 16; ++i) m = fmaxf(m, bf2f(arow[i]));
    float ssum = 0.f;
#pragma unroll
    for (int i = 0; i < 16; ++i) {
      float e = __expf(bf2f(arow[i]) - m);
      attn_s[tid][i] = e;
      ssum += e;
    }
    float inv = 1.f / ssum;
#pragma unroll
    for (int i = 0; i < 16; ++i) attn_s[tid][i] *= inv;
  }
  __syncthreads();

  // ---- meta precompute: 512 samples (32q x 16), 2 per thread ----
#pragma unroll
  for (int pass = 0; pass < 2; ++pass) {
    const int s = pass * 256 + tid;
    const int q = s >> 4, smp = s & 15;
    const int l = smp >> 2, p = smp & 3;
    const int W = (l == 0) ? 100 : (l == 1) ? 50 : (l == 2) ? 25 : 13;
    const int base = (l == 0) ? 0 : (l == 1) ? 10000 : (l == 2) ? 12500 : 13125;
    const float fW = (float)W;

    float ox = bf2f(oas[q * 48 + l * 8 + p * 2]);
    float oy = bf2f(oas[q * 48 + l * 8 + p * 2 + 1]);
    float rx = ref_s[q][l][0], ry = ref_s[q][l][1];
    float aw = attn_s[q][smp];
    float x = fmaf(rx, fW, ox) - 0.5f;
    float y = fmaf(ry, fW, oy) - 0.5f;  // H == W for all levels
    float x0f = floorf(x), y0f = floorf(y);
    float lw = x - x0f, lh = y - y0f;
    int x0 = (int)x0f, y0 = (int)y0f;
    int x1 = x0 + 1, y1 = y0 + 1;
    int xbase = min(max(x0, 0), W - 2);
    bool x0v = (x0 >= 0) && (x0 < W);
    bool x1v = (x1 >= 0) && (x1 < W);
    float ws0 = ((x0v && x0 == xbase) ? (1.f - lw) : 0.f) +
                ((x1v && x1 == xbase) ? lw : 0.f);
    float ws1 = ((x0v && x0 == xbase + 1) ? (1.f - lw) : 0.f) +
                ((x1v && x1 == xbase + 1) ? lw : 0.f);
    bool y0v = (y0 >= 0) && (y0 < W);
    bool y1v = (y1 >= 0) && (y1 < W);
    int yc0 = min(max(y0, 0), W - 1), yc1 = min(max(y1, 0), W - 1);
    float wy0 = y0v ? (1.f - lh) * aw : 0.f;
    float wy1 = y1v ? lh * aw : 0.f;
    const int posx = smp ^ (q & 7);  // bank swizzle, involution within row
    meta_w[q][posx] = make_uint2(
        (unsigned int)f2hbits(wy0 * ws0) |
            ((unsigned int)f2hbits(wy0 * ws1) << 16),
        (unsigned int)f2hbits(wy1 * ws0) |
            ((unsigned int)f2hbits(wy1 * ws1) << 16));
    meta_idx[q][posx] = (unsigned int)(yc0 * W + xbase + base) |
                        ((unsigned int)(yc1 * W + xbase + base) << 16);
  }
  __syncthreads();

  // ---- gather: lane = ql(8) x tp(8); depth-2 ping-pong, 16 samples ----
  {
    const int lane = tid & 63;
    const int wave = tid >> 6;
    const int ql = lane >> 3;     // query within wave
    const int q = wave * 8 + ql;  // 0..31 block-local query
    const int tp = lane & 7;      // pair-span octet
    const char* vbase = (const char*)vh +
                        ((size_t)h * M_ROWS + (size_t)b * LV_TOTAL) * 64;
    const unsigned int laneoff =
        (unsigned int)(tp >> 2) * 64 + (unsigned int)(tp & 3) * 16;
    const unsigned int sh = (lane & 4) << 2;  // 0 (slot0) or 16 (slot1)

#define PLOAD(C0, C1, IW, WW, smp)                                         \
  {                                                                        \
    const int pos_ = (smp) ^ ql;                                           \
    IW = meta_idx[q][pos_];                                                \
    WW = meta_w[q][pos_];                                                  \
    C0 = *(const uint4*)(vbase + (laneoff + ((IW & 0xffffu) << 6)));       \
    C1 = *(const uint4*)(vbase + (laneoff + ((IW >> 16) << 6)));           \
  }
#define PCONS(C0, C1, WW)                                                  \
  {                                                                        \
    unsigned int wr0 = WW.x >> sh, wr1 = WW.y >> sh;                       \
    MIX(acc[0], C0.x, wr0, 0); MIX(acc[1], C0.x, wr0, 1);                  \
    MIX(acc[2], C0.y, wr0, 0); MIX(acc[3], C0.y, wr0, 1);                  \
    MIX(acc[4], C0.z, wr0, 0); MIX(acc[5], C0.z, wr0, 1);                  \
    MIX(acc[6], C0.w, wr0, 0); MIX(acc[7], C0.w, wr0, 1);                  \
    MIX(acc[0], C1.x, wr1, 0); MIX(acc[1], C1.x, wr1, 1);                  \
    MIX(acc[2], C1.y, wr1, 0); MIX(acc[3], C1.y, wr1, 1);                  \
    MIX(acc[4], C1.z, wr1, 0); MIX(acc[5], C1.z, wr1, 1);                  \
    MIX(acc[6], C1.w, wr1, 0); MIX(acc[7], C1.w, wr1, 1);                  \
  }

    float acc[8];
#pragma unroll
    for (int j = 0; j < 8; ++j) acc[j] = 0.f;

    unsigned int iwA0, iwA1, iwB0, iwB1;
    uint2 wwA0, wwA1, wwB0, wwB1;
    uint4 A00, A01, A10, A11, B00, B01, B10, B11;
    PLOAD(A00, A01, iwA0, wwA0, 0);
    PLOAD(A10, A11, iwA1, wwA1, 1);
#pragma unroll
    for (int it = 0; it < 8; ++it) {
      if (it & 1) {
        if (it < 7) {
          PLOAD(A00, A01, iwA0, wwA0, 2 * it + 2);
          PLOAD(A10, A11, iwA1, wwA1, 2 * it + 3);
        }
        __builtin_amdgcn_sched_barrier(0);
        PCONS(B00, B01, wwB0);
        PCONS(B10, B11, wwB1);
      } else {
        if (it < 7) {
          PLOAD(B00, B01, iwB0, wwB0, 2 * it + 2);
          PLOAD(B10, B11, iwB1, wwB1, 2 * it + 3);
        }
        __builtin_amdgcn_sched_barrier(0);
        PCONS(A00, A01, wwA0);
        PCONS(A10, A11, wwA1);
      }
    }
#undef PLOAD
#undef PCONS

    // combine slot halves: lanes tp and tp^4 hold same dims, diff pixel
#pragma unroll
    for (int j = 0; j < 8; ++j) acc[j] += __shfl_xor(acc[j], 4, 64);

    const int qg = qb * QPB + q;
    if (((lane & 4) == 0) && qg < LQ) {
      uint4 pk;
      pk.x = (unsigned int)f2bf(acc[0]) | ((unsigned int)f2bf(acc[1]) << 16);
      pk.y = (unsigned int)f2bf(acc[2]) | ((unsigned int)f2bf(acc[3]) << 16);
      pk.z = (unsigned int)f2bf(acc[4]) | ((unsigned int)f2bf(acc[5]) << 16);
      pk.w = (unsigned int)f2bf(acc[6]) | ((unsigned int)f2bf(acc[7]) << 16);
      *(uint4*)(o_out + ((size_t)b * LQ + qg) * EMBED + h * HEAD_DIM +
                (tp & 3) * 8) = pk;
    }
  }
}

// ---------------------------------------------------------------------------
extern "C" void kernel_launch(void* const* d_in, const int* in_sizes, int n_in,
                              void* d_out, int out_size, void* d_ws,
                              size_t ws_size, hipStream_t stream) {
  const float* query = (const float*)d_in[0];
  const float* refpts = (const float*)d_in[1];
  const float* value = (const float*)d_in[2];
  const uint8_t* mask = (const uint8_t*)d_in[3];
  // d_in[4] = spatial_shapes (hardcoded: {100,100},{50,50},{25,25},{13,13})
  const float* W_off = (const float*)d_in[5];
  const float* b_off = (const float*)d_in[6];
  const float* W_attn = (const float*)d_in[7];
  const float* b_attn = (const float*)d_in[8];
  const float* W_val = (const float*)d_in[9];
  const float* b_val = (const float*)d_in[10];
  const float* W_out = (const float*)d_in[11];
  const float* b_out = (const float*)d_in[12];
  float* out = (float*)d_out;

  // ws layout (bytes); o_ws aliases vbf (dead after gemm_fused01)
  char* ws = (char*)d_ws;
  unsigned short* vh_ws = (unsigned short*)ws;  // f16 [8][26588][32] = 13,613,056
  unsigned short* oah_ws =
      (unsigned short*)(ws + 13613056);  // bf16 [8][26588][48] = 20,419,584
  unsigned short* vbf_ws =
      (unsigned short*)(ws + 34032640);  // bf16 [26588][256] = 13,613,056
  unsigned short* qbf_ws =
      (unsigned short*)(ws + 47645696);  // bf16 [26588][256] = 13,613,056
  unsigned short* wt_val =
      (unsigned short*)(ws + 61258752);            // 131072 B
  unsigned short* wt_oa = wt_val + 256 * 256;      // 196608 B
  unsigned short* wt_out = wt_oa + 384 * 256;      // 131072 B
  unsigned short* o_ws = vbf_ws;  // alias: vbf dead once fused01 completes

  prep_wt_kernel<<<896, 256, 0, stream>>>(W_val, W_off, W_attn, W_out, wt_val,
                                          wt_oa, wt_out);

  // pre-convert A matrices to bf16 (identical rounding to in-GEMM f2bf)
  const int N8 = M_ROWS * EMBED / 8;  // 850,816
  conv_bf16_kernel<<<dim3((N8 + 255) / 256, 2), 256, 0, stream>>>(
      value, query, vbf_ws, qbf_ws, N8);

  // fused: flat 2080 blocks, XCD-chunked (A slice pinned per XCD L2)
  gemm_fused01_kernel<<<RB_N * 10, 256, 0, stream>>>(
      vbf_ws, qbf_ws, wt_val, wt_oa, b_val, b_off, b_attn, mask, vh_ws,
      oah_ws, M_ROWS);

  // flat 1D grid: h = bid&7 -> XCD-pinned head slices
  gather_kernel<<<QB_N * HEADS * BS, 256, 0, stream>>>(
      refpts, (const __half*)vh_ws, oah_ws, o_ws);

  // out = o @ W_out + b_out -> f32 (flat 832, XCD-chunked)
  gemm_out_kernel<<<RB_N * 4, 256, 0, stream>>>(o_ws, wt_out, b_out, out,
                                                M_ROWS);
}

// Round 24
// 105.186 us; speedup vs baseline: 1.1594x; 1.0363x over previous
//
#include <hip/hip_runtime.h>
#include <hip/hip_bf16.h>
#include <hip/hip_fp16.h>
#include <stdint.h>

#define EMBED 256
#define HEADS 8
#define LEVELS 4
#define POINTS 4
#define HEAD_DIM 32
#define BS 2
#define LV_TOTAL 13294
#define LQ LV_TOTAL
#define TP 128 /* HEADS*LEVELS*POINTS */
#define M_ROWS (BS * LV_TOTAL) /* 26588 */
#define QPB 32 /* queries per gather block (1 head per block) */
#define QB_N 416 /* ceil(LQ/QPB) */
#define RB_N 208 /* ceil(M_ROWS/128) = 8*26, XCD-chunkable */
#define CONV_N8 (M_ROWS * EMBED / 8) /* 850816/8 = 850,816? no: 26588*256/8 = 850,816 */
#define CONV_BLKS ((CONV_N8 + 255) / 256) /* 3324 */

typedef __attribute__((ext_vector_type(8))) short bf16x8;
typedef __attribute__((ext_vector_type(4))) float f32x4;

static __device__ __forceinline__ unsigned short f2bf(float x) {
  __hip_bfloat16 h = __float2bfloat16(x);
  return *reinterpret_cast<unsigned short*>(&h);
}
static __device__ __forceinline__ float bf2f(unsigned short u) {
  return __uint_as_float(((unsigned int)u) << 16);
}
static __device__ __forceinline__ unsigned short f2hbits(float x) {
  __half h = __float2half(x);
  return *reinterpret_cast<unsigned short*>(&h);
}

// v_fma_mix_f32: acc(f32) += f16(sel vs of pk) * f16(low half of w)
#define MIX(acc, pk, w, vs)                                              \
  asm("v_fma_mix_f32 %0, %1, %2, %0 op_sel:[" #vs                        \
      ",0,0] op_sel_hi:[1,1,0]"                                          \
      : "+v"(acc)                                                        \
      : "v"(pk), "v"(w))

// ---------------------------------------------------------------------------
// prep_all: ONE launch for weight transpose+convert AND value/query bf16
// conversion.  Flat grid 896 + 2*CONV_BLKS blocks:
//   [0,896)                      weight prep (as before)
//   [896, 896+CONV_BLKS)         value f32->bf16
//   [896+CONV_BLKS, +2*CONV_BLKS) query f32->bf16
// ---------------------------------------------------------------------------
__global__ __launch_bounds__(256) void prep_all_kernel(
    const float* __restrict__ W_val, const float* __restrict__ W_off,
    const float* __restrict__ W_attn, const float* __restrict__ W_out,
    const float* __restrict__ value, const float* __restrict__ query,
    unsigned short* __restrict__ WT_val, unsigned short* __restrict__ WT_oa,
    unsigned short* __restrict__ WT_out, unsigned short* __restrict__ vbf,
    unsigned short* __restrict__ qbf) {
  const int bid = blockIdx.x;
  if (bid < 896) {
    const int k = threadIdx.x;  // 0..255
    const float* src;
    unsigned short* dst;
    int n, N_src;
    if (bid < 256) {
      src = W_val; dst = WT_val; n = bid; N_src = 256;
    } else if (bid < 512) {
      src = W_off; dst = WT_oa; n = bid - 256; N_src = 256;
    } else if (bid < 640) {
      src = W_attn; dst = WT_oa + 256 * 256; n = bid - 512; N_src = 128;
    } else {
      src = W_out; dst = WT_out; n = bid - 640; N_src = 256;
    }
    dst[n * 256 + k] = f2bf(src[(size_t)k * N_src + n]);
  } else {
    const int cb = bid - 896;
    const bool isQ = cb >= CONV_BLKS;
    const int i = (isQ ? cb - CONV_BLKS : cb) * 256 + threadIdx.x;
    const float* in = isQ ? query : value;
    unsigned short* out = isQ ? qbf : vbf;
    if (i < CONV_N8) {
      float4 p0 = *(const float4*)(in + (size_t)i * 8);
      float4 p1 = *(const float4*)(in + (size_t)i * 8 + 4);
      uint4 o;
      o.x = (unsigned int)f2bf(p0.x) | ((unsigned int)f2bf(p0.y) << 16);
      o.y = (unsigned int)f2bf(p0.z) | ((unsigned int)f2bf(p0.w) << 16);
      o.z = (unsigned int)f2bf(p1.x) | ((unsigned int)f2bf(p1.y) << 16);
      o.w = (unsigned int)f2bf(p1.z) | ((unsigned int)f2bf(p1.w) << 16);
      *(uint4*)(out + (size_t)i * 8) = o;
    }
  }
}

// ---------------------------------------------------------------------------
// Round-9 GEMM body (PROVEN): one 64-col strip x 128 rows; B panel (32 KB)
// in LDS w/ XOR swizzle; per kk: 2 bf16 A-frags, 4 ds_read_b128, 8 MFMA.
// (strip, rowblk) passed explicitly for XCD-chunked flat grids.
// OUT_MODE: 0=f32, 1=bf16, 2=f16 head-major vh, 3=bf16 head-major oa_h.
// ---------------------------------------------------------------------------
template <int NTOT, int OUT_MODE, bool MASKED, bool SPLIT_BIAS>
static __device__ __forceinline__ void gemm_body(
    unsigned short* bpanel, const unsigned short* __restrict__ Ab,
    const unsigned short* __restrict__ BT, const float* __restrict__ bias0,
    const float* __restrict__ bias1, const uint8_t* __restrict__ mask,
    void* __restrict__ Cv, int M, int strip, int rowblk) {
  const int tid = threadIdx.x;
  const int col0 = strip * 64;

  // ---- stage B panel (64 cols x 256 k, bf16), XOR-swizzled ----
#pragma unroll
  for (int it = 0; it < 8; ++it) {
    int c = it * 256 + tid;  // chunk id 0..2047 (16B chunks)
    int col = c >> 5;        // 0..63
    int kc = c & 31;         // 16B chunk within the col's 512B row
    uint4 vdat = *(const uint4*)(BT + ((size_t)(col0 + col)) * 256 + kc * 8);
    int byteoff = (col << 9) + ((kc << 4) ^ ((col & 7) << 4));
    *(uint4*)((char*)bpanel + byteoff) = vdat;
  }
  __syncthreads();

  const int wave = tid >> 6;
  const int lane = tid & 63;
  const int lr = lane & 15;
  const int kq = lane >> 4;  // 0..3
  const int rowW = rowblk * 128 + wave * 16;
  const int ar0 = min(rowW + lr, M - 1);
  const int ar1 = min(rowW + 64 + lr, M - 1);

  f32x4 acc[2][4];
#pragma unroll
  for (int ri = 0; ri < 2; ++ri)
#pragma unroll
    for (int c = 0; c < 4; ++c) acc[ri][c] = (f32x4){0.f, 0.f, 0.f, 0.f};

#pragma unroll
  for (int kk = 0; kk < 8; ++kk) {
    const int k0 = kk * 32 + kq * 8;
    bf16x8 a0 = *(const bf16x8*)(Ab + (size_t)ar0 * 256 + k0);
    bf16x8 a1 = *(const bf16x8*)(Ab + (size_t)ar1 * 256 + k0);
#pragma unroll
    for (int c = 0; c < 4; ++c) {
      const int col = c * 16 + lr;
      const int byteoff = (col << 9) + (((k0 * 2)) ^ ((col & 7) << 4));
      bf16x8 bfrag = *(const bf16x8*)((const char*)bpanel + byteoff);
      acc[0][c] =
          __builtin_amdgcn_mfma_f32_16x16x32_bf16(a0, bfrag, acc[0][c], 0, 0, 0);
      acc[1][c] =
          __builtin_amdgcn_mfma_f32_16x16x32_bf16(a1, bfrag, acc[1][c], 0, 0, 0);
    }
  }

  // epilogue: D col = lane&15, row = (lane>>4)*4 + i   [m89-verified]
#pragma unroll
  for (int c = 0; c < 4; ++c) {
    const int col = col0 + c * 16 + lr;
    float bv;
    if constexpr (SPLIT_BIAS)
      bv = (col < 256) ? bias0[col] : bias1[col - 256];
    else
      bv = bias0[col];
#pragma unroll
    for (int ri = 0; ri < 2; ++ri) {
#pragma unroll
      for (int i = 0; i < 4; ++i) {
        const int row = rowW + ri * 64 + kq * 4 + i;
        if (row < M) {
          float o = acc[ri][c][i] + bv;
          if constexpr (MASKED) {
            if (mask[row]) o = 0.f;
          }
          if constexpr (OUT_MODE == 0) {
            ((float*)Cv)[(size_t)row * NTOT + col] = o;
          } else if constexpr (OUT_MODE == 1) {
            ((unsigned short*)Cv)[(size_t)row * NTOT + col] = f2bf(o);
          } else if constexpr (OUT_MODE == 2) {
            ((unsigned short*)Cv)[(size_t)(col >> 5) * ((size_t)M * 32) +
                                  (size_t)row * 32 + (col & 31)] = f2hbits(o);
          } else {
            // head-major oa: [h][row][48], off cols 0..31, attn cols 32..47
            int hh, w_;
            if (col < 256) { hh = col >> 5; w_ = col & 31; }
            else { int c2 = col - 256; hh = c2 >> 4; w_ = 32 + (c2 & 15); }
            ((unsigned short*)Cv)[((size_t)hh * M + row) * 48 + w_] = f2bf(o);
          }
        }
      }
    }
  }
}

// fat kernel, flat grid 2080 = 8 XCD-chunks x 26 rowblks x 10 strips.
__global__ __launch_bounds__(256) void gemm_fused01_kernel(
    const unsigned short* __restrict__ value_bf,
    const unsigned short* __restrict__ query_bf,
    const unsigned short* __restrict__ wt_val,
    const unsigned short* __restrict__ wt_oa, const float* __restrict__ b_val,
    const float* __restrict__ b_off, const float* __restrict__ b_attn,
    const uint8_t* __restrict__ mask, unsigned short* __restrict__ vh,
    unsigned short* __restrict__ oah, int M) {
  __shared__ uint4 bpanel4[2048];  // 32 KB
  unsigned short* bp = (unsigned short*)bpanel4;
  const int bid = blockIdx.x;
  const int xcd = bid & 7;
  const int idx = bid >> 3;            // 0..259
  const int rb = xcd * 26 + idx / 10;  // 0..207
  const int strip = idx % 10;
  if (strip < 4)
    gemm_body<256, 2, true, false>(bp, value_bf, wt_val, b_val, nullptr, mask,
                                   vh, M, strip, rb);
  else
    gemm_body<384, 3, false, true>(bp, query_bf, wt_oa, b_off, b_attn,
                                   nullptr, oah, M, strip - 4, rb);
}

// flat grid 832 = 8 x 26 x 4: same XCD-chunked mapping for the o matrix.
__global__ __launch_bounds__(256) void gemm_out_kernel(
    const unsigned short* __restrict__ o_in,
    const unsigned short* __restrict__ wt_out, const float* __restrict__ b_out,
    float* __restrict__ out, int M) {
  __shared__ uint4 bpanel4[2048];
  unsigned short* bp = (unsigned short*)bpanel4;
  const int bid = blockIdx.x;
  const int xcd = bid & 7;
  const int idx = bid >> 3;                // 0..103
  const int rb = xcd * 26 + (idx >> 2);    // 0..207
  const int strip = idx & 3;
  gemm_body<256, 0, false, false>(bp, o_in, wt_out, b_out, nullptr, nullptr,
                                  out, M, strip, rb);
}

// ---------------------------------------------------------------------------
// gather_kernel (HEAD-PARTITIONED + h->XCD mapping, round-22/23 PROVEN):
// flat 1D grid 6656; h = bid&7 pins each head's 1.7 MB vh slice to one
// XCD's L2 (FETCH 60 -> 20 MB).  Depth-2 ping-pong + sched_barrier(0).
// NEW: meta (idx + 4 f16 weights) packed in ONE uint4 -> single
// ds_read_b128 per sample instead of b32+b64 (fewer LDS issues).
// ---------------------------------------------------------------------------
__global__ __launch_bounds__(256) void gather_kernel(
    const float* __restrict__ refpts,
    const __half* __restrict__ vh,           // f16 head-major [8][M][32]
    const unsigned short* __restrict__ oah,  // bf16 head-major [8][M][48]
    unsigned short* __restrict__ o_out) {    // bf16 (BS*LQ, 256)
  __shared__ unsigned short oas[QPB * 48];  // 3 KB raw bf16 [q][48]
  __shared__ float attn_s[QPB][16];         // 2 KB
  __shared__ float ref_s[QPB][LEVELS][2];   // 1 KB
  __shared__ uint4 meta_pk[QPB][16];        // 8 KB {idxpair, w01, w23, pad}

  // flat bid -> (h, b, qb): h fastest (XCD-pinned), then qb, then b
  const int bid = blockIdx.x;        // 0..6655
  const int h = bid & 7;             // head -> XCD (round-robin, validated)
  const int rest = bid >> 3;         // 0..831
  const int b = rest / QB_N;         // batch
  const int qb = rest - b * QB_N;    // query block 0..415
  const int tid = threadIdx.x;

  // ---- stage oa head-slice: 32 rows x 48 shorts (96 B/row, 6 uint4) ----
  {
    int row = tid >> 3, j = tid & 7;
    if (j < 6) {
      int qg = min(qb * QPB + row, LQ - 1);
      *(uint4*)(oas + row * 48 + j * 8) = *(const uint4*)(
          oah + ((size_t)h * M_ROWS + (size_t)b * LQ + qg) * 48 + j * 8);
    }
  }
  // ---- reference points: 32 q x 8 vals ----
  {
    int q = tid >> 3, rem = tid & 7;
    int qg = min(qb * QPB + q, LQ - 1);
    ref_s[q][rem >> 1][rem & 1] = refpts[((size_t)b * LQ + qg) * 8 + rem];
  }
  __syncthreads();

  // ---- softmax per q over this head's 16 logits (oas cols 32..47) ----
  if (tid < QPB) {
    const unsigned short* arow = oas + tid * 48 + 32;
    float m = bf2f(arow[0]);
#pragma unroll
    for (int i = 1; i < 16; ++i) m = fmaxf(m, bf2f(arow[i]));
    float ssum = 0.f;
#pragma unroll
    for (int i = 0; i < 16; ++i) {
      float e = __expf(bf2f(arow[i]) - m);
      attn_s[tid][i] = e;
      ssum += e;
    }
    float inv = 1.f / ssum;
#pragma unroll
    for (int i = 0; i < 16; ++i) attn_s[tid][i] *= inv;
  }
  __syncthreads();

  // ---- meta precompute: 512 samples (32q x 16), 2 per thread ----
#pragma unroll
  for (int pass = 0; pass < 2; ++pass) {
    const int s = pass * 256 + tid;
    const int q = s >> 4, smp = s & 15;
    const int l = smp >> 2, p = smp & 3;
    const int W = (l == 0) ? 100 : (l == 1) ? 50 : (l == 2) ? 25 : 13;
    const int base = (l == 0) ? 0 : (l == 1) ? 10000 : (l == 2) ? 12500 : 13125;
    const float fW = (float)W;

    float ox = bf2f(oas[q * 48 + l * 8 + p * 2]);
    float oy = bf2f(oas[q * 48 + l * 8 + p * 2 + 1]);
    float rx = ref_s[q][l][0], ry = ref_s[q][l][1];
    float aw = attn_s[q][smp];
    float x = fmaf(rx, fW, ox) - 0.5f;
    float y = fmaf(ry, fW, oy) - 0.5f;  // H == W for all levels
    float x0f = floorf(x), y0f = floorf(y);
    float lw = x - x0f, lh = y - y0f;
    int x0 = (int)x0f, y0 = (int)y0f;
    int x1 = x0 + 1, y1 = y0 + 1;
    int xbase = min(max(x0, 0), W - 2);
    bool x0v = (x0 >= 0) && (x0 < W);
    bool x1v = (x1 >= 0) && (x1 < W);
    float ws0 = ((x0v && x0 == xbase) ? (1.f - lw) : 0.f) +
                ((x1v && x1 == xbase) ? lw : 0.f);
    float ws1 = ((x0v && x0 == xbase + 1) ? (1.f - lw) : 0.f) +
                ((x1v && x1 == xbase + 1) ? lw : 0.f);
    bool y0v = (y0 >= 0) && (y0 < W);
    bool y1v = (y1 >= 0) && (y1 < W);
    int yc0 = min(max(y0, 0), W - 1), yc1 = min(max(y1, 0), W - 1);
    float wy0 = y0v ? (1.f - lh) * aw : 0.f;
    float wy1 = y1v ? lh * aw : 0.f;
    const int posx = smp ^ (q & 7);  // bank swizzle, involution within row
    meta_pk[q][posx] = make_uint4(
        (unsigned int)(yc0 * W + xbase + base) |
            ((unsigned int)(yc1 * W + xbase + base) << 16),
        (unsigned int)f2hbits(wy0 * ws0) |
            ((unsigned int)f2hbits(wy0 * ws1) << 16),
        (unsigned int)f2hbits(wy1 * ws0) |
            ((unsigned int)f2hbits(wy1 * ws1) << 16),
        0u);
  }
  __syncthreads();

  // ---- gather: lane = ql(8) x tp(8); depth-2 ping-pong, 16 samples ----
  {
    const int lane = tid & 63;
    const int wave = tid >> 6;
    const int ql = lane >> 3;     // query within wave
    const int q = wave * 8 + ql;  // 0..31 block-local query
    const int tp = lane & 7;      // pair-span octet
    const char* vbase = (const char*)vh +
                        ((size_t)h * M_ROWS + (size_t)b * LV_TOTAL) * 64;
    const unsigned int laneoff =
        (unsigned int)(tp >> 2) * 64 + (unsigned int)(tp & 3) * 16;
    const unsigned int sh = (lane & 4) << 2;  // 0 (slot0) or 16 (slot1)

#define PLOAD(C0, C1, W0, W1, smp)                                         \
  {                                                                        \
    const int pos_ = (smp) ^ ql;                                           \
    uint4 mp_ = meta_pk[q][pos_];                                          \
    W0 = mp_.y; W1 = mp_.z;                                                \
    C0 = *(const uint4*)(vbase + (laneoff + ((mp_.x & 0xffffu) << 6)));    \
    C1 = *(const uint4*)(vbase + (laneoff + ((mp_.x >> 16) << 6)));        \
  }
#define PCONS(C0, C1, W0, W1)                                              \
  {                                                                        \
    unsigned int wr0 = W0 >> sh, wr1 = W1 >> sh;                           \
    MIX(acc[0], C0.x, wr0, 0); MIX(acc[1], C0.x, wr0, 1);                  \
    MIX(acc[2], C0.y, wr0, 0); MIX(acc[3], C0.y, wr0, 1);                  \
    MIX(acc[4], C0.z, wr0, 0); MIX(acc[5], C0.z, wr0, 1);                  \
    MIX(acc[6], C0.w, wr0, 0); MIX(acc[7], C0.w, wr0, 1);                  \
    MIX(acc[0], C1.x, wr1, 0); MIX(acc[1], C1.x, wr1, 1);                  \
    MIX(acc[2], C1.y, wr1, 0); MIX(acc[3], C1.y, wr1, 1);                  \
    MIX(acc[4], C1.z, wr1, 0); MIX(acc[5], C1.z, wr1, 1);                  \
    MIX(acc[6], C1.w, wr1, 0); MIX(acc[7], C1.w, wr1, 1);                  \
  }

    float acc[8];
#pragma unroll
    for (int j = 0; j < 8; ++j) acc[j] = 0.f;

    unsigned int wA0, wA1, wB0, wB1;
    uint4 A00, A01, A10, A11, B00, B01, B10, B11;
    PLOAD(A00, A01, wA0, wA1, 0);   // sample 0 into A-even slots
    PLOAD(A10, A11, wB0, wB1, 1);   // sample 1 into A-odd slots
    // NOTE: keep exact round-22 structure: A-set = samples {0,1},
    // B-set = samples {2,3}, alternating.
    unsigned int wA0b = wB0, wA1b = wB1;
    unsigned int wB0a, wB1a, wB0b, wB1b;
#pragma unroll
    for (int it = 0; it < 8; ++it) {
      if (it & 1) {
        if (it < 7) {
          PLOAD(A00, A01, wA0, wA1, 2 * it + 2);
          PLOAD(A10, A11, wA0b, wA1b, 2 * it + 3);
        }
        __builtin_amdgcn_sched_barrier(0);
        PCONS(B00, B01, wB0a, wB1a);
        PCONS(B10, B11, wB0b, wB1b);
      } else {
        if (it < 7) {
          PLOAD(B00, B01, wB0a, wB1a, 2 * it + 2);
          PLOAD(B10, B11, wB0b, wB1b, 2 * it + 3);
        }
        __builtin_amdgcn_sched_barrier(0);
        PCONS(A00, A01, wA0, wA1);
        PCONS(A10, A11, wA0b, wA1b);
      }
    }
#undef PLOAD
#undef PCONS

    // combine slot halves: lanes tp and tp^4 hold same dims, diff pixel
#pragma unroll
    for (int j = 0; j < 8; ++j) acc[j] += __shfl_xor(acc[j], 4, 64);

    const int qg = qb * QPB + q;
    if (((lane & 4) == 0) && qg < LQ) {
      uint4 pk;
      pk.x = (unsigned int)f2bf(acc[0]) | ((unsigned int)f2bf(acc[1]) << 16);
      pk.y = (unsigned int)f2bf(acc[2]) | ((unsigned int)f2bf(acc[3]) << 16);
      pk.z = (unsigned int)f2bf(acc[4]) | ((unsigned int)f2bf(acc[5]) << 16);
      pk.w = (unsigned int)f2bf(acc[6]) | ((unsigned int)f2bf(acc[7]) << 16);
      *(uint4*)(o_out + ((size_t)b * LQ + qg) * EMBED + h * HEAD_DIM +
                (tp & 3) * 8) = pk;
    }
  }
}

// ---------------------------------------------------------------------------
extern "C" void kernel_launch(void* const* d_in, const int* in_sizes, int n_in,
                              void* d_out, int out_size, void* d_ws,
                              size_t ws_size, hipStream_t stream) {
  const float* query = (const float*)d_in[0];
  const float* refpts = (const float*)d_in[1];
  const float* value = (const float*)d_in[2];
  const uint8_t* mask = (const uint8_t*)d_in[3];
  // d_in[4] = spatial_shapes (hardcoded: {100,100},{50,50},{25,25},{13,13})
  const float* W_off = (const float*)d_in[5];
  const float* b_off = (const float*)d_in[6];
  const float* W_attn = (const float*)d_in[7];
  const float* b_attn = (const float*)d_in[8];
  const float* W_val = (const float*)d_in[9];
  const float* b_val = (const float*)d_in[10];
  const float* W_out = (const float*)d_in[11];
  const float* b_out = (const float*)d_in[12];
  float* out = (float*)d_out;

  // ws layout (bytes); o_ws aliases vbf (dead after gemm_fused01)
  char* ws = (char*)d_ws;
  unsigned short* vh_ws = (unsigned short*)ws;  // f16 [8][26588][32] = 13,613,056
  unsigned short* oah_ws =
      (unsigned short*)(ws + 13613056);  // bf16 [8][26588][48] = 20,419,584
  unsigned short* vbf_ws =
      (unsigned short*)(ws + 34032640);  // bf16 [26588][256] = 13,613,056
  unsigned short* qbf_ws =
      (unsigned short*)(ws + 47645696);  // bf16 [26588][256] = 13,613,056
  unsigned short* wt_val =
      (unsigned short*)(ws + 61258752);            // 131072 B
  unsigned short* wt_oa = wt_val + 256 * 256;      // 196608 B
  unsigned short* wt_out = wt_oa + 384 * 256;      // 131072 B
  unsigned short* o_ws = vbf_ws;  // alias: vbf dead once fused01 completes

  // ONE prep launch: weight transpose+convert + value/query bf16 conversion
  prep_all_kernel<<<896 + 2 * CONV_BLKS, 256, 0, stream>>>(
      W_val, W_off, W_attn, W_out, value, query, wt_val, wt_oa, wt_out,
      vbf_ws, qbf_ws);

  // fused: flat 2080 blocks, XCD-chunked (A slice pinned per XCD L2)
  gemm_fused01_kernel<<<RB_N * 10, 256, 0, stream>>>(
      vbf_ws, qbf_ws, wt_val, wt_oa, b_val, b_off, b_attn, mask, vh_ws,
      oah_ws, M_ROWS);

  // flat 1D grid: h = bid&7 -> XCD-pinned head slices
  gather_kernel<<<QB_N * HEADS * BS, 256, 0, stream>>>(
      refpts, (const __half*)vh_ws, oah_ws, o_ws);

  // out = o @ W_out + b_out -> f32 (flat 832, XCD-chunked)
  gemm_out_kernel<<<RB_N * 4, 256, 0, stream>>>(o_ws, wt_out, b_out, out,
                                                M_ROWS);
}